// Round 8
// baseline (224.379 us; speedup 1.0000x reference)
//
#include <hip/hip_runtime.h>
#include <math.h>
#include <stdint.h>

#define PI2 6.28318530717958647692f

typedef __bf16 bf16x8 __attribute__((ext_vector_type(8)));
typedef float f32x4 __attribute__((ext_vector_type(4)));

typedef __attribute__((address_space(1))) const void gvoid_t;
typedef __attribute__((address_space(3))) void lvoid_t;

__device__ __forceinline__ void g2l16(const void* g, void* l) {
    __builtin_amdgcn_global_load_lds(
        reinterpret_cast<gvoid_t*>(reinterpret_cast<uintptr_t>(g)),
        reinterpret_cast<lvoid_t*>(reinterpret_cast<uintptr_t>(l)),
        16, 0, 0);
}

__device__ __forceinline__ short f2bf(float f) {
    unsigned u = __float_as_uint(f);
    u += 0x7FFFu + ((u >> 16) & 1u);          // round-to-nearest-even
    return (short)(u >> 16);
}

__device__ __forceinline__ unsigned pack2bf(float a, float b) {
    return (unsigned)(unsigned short)f2bf(a) |
           ((unsigned)(unsigned short)f2bf(b) << 16);
}

__device__ __forceinline__ float bflo(unsigned v) { return __uint_as_float(v << 16); }
__device__ __forceinline__ float bfhi(unsigned v) { return __uint_as_float(v & 0xFFFF0000u); }

// XCD-locality swizzle (G must be a multiple of 8 -> bijective).
__device__ __forceinline__ int xcd_swizzle(int blk, int G) {
    return (blk & 7) * (G >> 3) + (blk >> 3);
}

// ---------------------------------------------------------------------------
// Fused aux kernel, 8 outputs per thread (fold region does 8+8), 8192 blocks.
// Regions (i8 = global element index, 8 shorts per thread):
//   [0,      2M):  xe/xo radix-2 fold of x (1024x2048 each, bf16)
//   [2M,     6M):  B1f folded DFT basis (2048x2048)
//   [6M,    10M):  VcatT (2048x2048): VcatT[f][kk] = V?[kk][col(f)]
//                  (TRANSPOSED vs prior rounds -- W2 contracts over kk)
//   [10M,   12M):  B2 (1024x2048), B2[p][k] = basis_p(k) * S[k]
//   [12M,   16M):  Ucat (4096x1024) = [Ur | Ui]
// ---------------------------------------------------------------------------
__global__ __launch_bounds__(256) void aux_all8(
    const float* __restrict__ x,
    const float* __restrict__ Ur, const float* __restrict__ Ui,
    const float* __restrict__ S,
    const float* __restrict__ Vr, const float* __restrict__ Vi,
    short* __restrict__ xe, short* __restrict__ xo,
    short* __restrict__ B1f, short* __restrict__ VcatT,
    short* __restrict__ B2, short* __restrict__ Ucat)
{
    unsigned i8 = (blockIdx.x * 256u + threadIdx.x) * 8u;
    if (i8 < 2097152u) {
        // radix-2 fold: xe = x[:, :2048] + x[:, 2048:], xo = difference
        unsigned i = i8;
        int r = i >> 11, j0 = i & 2047;
        const float* xr = x + (size_t)r * 4096 + j0;
        float4 a0 = ((const float4*)xr)[0], a1 = ((const float4*)xr)[1];
        float4 b0 = ((const float4*)(xr + 2048))[0],
               b1 = ((const float4*)(xr + 2048))[1];
        uint4 oe = {pack2bf(a0.x + b0.x, a0.y + b0.y),
                    pack2bf(a0.z + b0.z, a0.w + b0.w),
                    pack2bf(a1.x + b1.x, a1.y + b1.y),
                    pack2bf(a1.z + b1.z, a1.w + b1.w)};
        *(uint4*)(xe + i) = oe;
        uint4 oo = {pack2bf(a0.x - b0.x, a0.y - b0.y),
                    pack2bf(a0.z - b0.z, a0.w - b0.w),
                    pack2bf(a1.x - b1.x, a1.y - b1.y),
                    pack2bf(a1.z - b1.z, a1.w - b1.w)};
        *(uint4*)(xo + i) = oo;
    } else if (i8 < 6291456u) {
        unsigned i = i8 - 2097152u;
        int r = i >> 11, j0 = i & 2047;
        const float inv_n = 1.0f / 4096.0f;
        float v[8];
        if (r < 512) {
            if (r == 0) {
                #pragma unroll
                for (int u = 0; u < 8; ++u) v[u] = inv_n;
            } else {
                #pragma unroll
                for (int u = 0; u < 8; ++u) {
                    int t = (r * (j0 + u)) & 2047;
                    v[u] = 2.0f * inv_n * cosf((float)t * (PI2 / 2048.0f));
                }
            }
        } else if (r < 1024) {
            int m = r - 512;
            #pragma unroll
            for (int u = 0; u < 8; ++u) {
                int t = (m * (j0 + u)) & 2047;
                v[u] = -2.0f * inv_n * sinf((float)t * (PI2 / 2048.0f));
            }
        } else if (r < 1536) {
            int c = 2 * (r - 1024) + 1;
            #pragma unroll
            for (int u = 0; u < 8; ++u) {
                int t = (c * (j0 + u)) & 4095;
                v[u] = 2.0f * inv_n * cosf((float)t * (PI2 / 4096.0f));
            }
        } else {
            int m = 2 * (r - 1536) + 1;
            #pragma unroll
            for (int u = 0; u < 8; ++u) {
                int t = (m * (j0 + u)) & 4095;
                v[u] = -2.0f * inv_n * sinf((float)t * (PI2 / 4096.0f));
            }
        }
        uint4 o = {pack2bf(v[0], v[1]), pack2bf(v[2], v[3]),
                   pack2bf(v[4], v[5]), pack2bf(v[6], v[7])};
        *(uint4*)(B1f + i) = o;
    } else if (i8 < 10485760u) {
        // VcatT[f][kk] = V?[kk][2*cc + (cls>>1)], f = cls*512+cc.
        // One f-row per block: thread slot t_lin -> f = t_lin>>8,
        // kk0 = (t_lin&255)*8. Write is coalesced; reads are 8 strided
        // dwords/thread (column gather), absorbed by L2/L3.
        unsigned e = i8 - 6291456u;
        int t_lin = e >> 3;
        int f   = t_lin >> 8;
        int kk0 = (t_lin & 255) << 3;
        int cls = f >> 9, cc = f & 511;
        const float* src = ((cls & 1) ? Vi : Vr) + 2 * cc + (cls >> 1);
        float v[8];
        #pragma unroll
        for (int u = 0; u < 8; ++u)
            v[u] = src[(size_t)(kk0 + u) * 1024];
        uint4 o = {pack2bf(v[0], v[1]), pack2bf(v[2], v[3]),
                   pack2bf(v[4], v[5]), pack2bf(v[6], v[7])};
        *(uint4*)(VcatT + e) = o;
    } else if (i8 < 12582912u) {
        // B2[p][k] = basis_p(k) * S[k], p-major (1024 x 2048)
        unsigned i = i8 - 10485760u;
        int p = i >> 11, k0 = i & 2047;
        float4 s0 = *(const float4*)(S + k0);
        float4 s1 = *(const float4*)(S + k0 + 4);
        float sv[8] = {s0.x, s0.y, s0.z, s0.w, s1.x, s1.y, s1.z, s1.w};
        const float inv_n = 1.0f / 2048.0f;
        float v[8];
        if (p == 0) {
            #pragma unroll
            for (int u = 0; u < 8; ++u) v[u] = inv_n * sv[u];
        } else if (p < 512) {
            #pragma unroll
            for (int u = 0; u < 8; ++u) {
                int t = (p * (k0 + u)) & 2047;
                v[u] = 2.0f * inv_n * cosf((float)t * (PI2 / 2048.0f)) * sv[u];
            }
        } else {
            int q = p - 512;
            #pragma unroll
            for (int u = 0; u < 8; ++u) {
                int t = (q * (k0 + u)) & 2047;
                v[u] = -2.0f * inv_n * sinf((float)t * (PI2 / 2048.0f)) * sv[u];
            }
        }
        uint4 o = {pack2bf(v[0], v[1]), pack2bf(v[2], v[3]),
                   pack2bf(v[4], v[5]), pack2bf(v[6], v[7])};
        *(uint4*)(B2 + i) = o;
    } else {
        unsigned i = i8 - 12582912u;
        int o_ = i >> 10, c = i & 1023;
        const float* src = (c < 512) ? (Ur + (size_t)o_ * 512 + c)
                                     : (Ui + (size_t)o_ * 512 + (c - 512));
        float4 a = ((const float4*)src)[0], b = ((const float4*)src)[1];
        uint4 o = {pack2bf(a.x, a.y), pack2bf(a.z, a.w),
                   pack2bf(b.x, b.y), pack2bf(b.z, b.w)};
        *(uint4*)(Ucat + i) = o;
    }
}

// ---------------------------------------------------------------------------
// 128x128 MFMA tile core, BK=64, XOR-swizzled LDS, double-buffered
// (round-5 proven): next K-tile's global_load_lds issues BEFORE the compute
// phase; one __syncthreads() per K-step. LDS 64 KB/block -> 2 blocks/CU.
// ---------------------------------------------------------------------------
__device__ __forceinline__ void tile_core(
    const short* __restrict__ A, int lda,
    const short* __restrict__ B, int ldb, int K,
    short* As, short* Bs, int bm, int bn, f32x4 (&acc)[4][4])
{
    const int tid  = threadIdx.x;
    const int wave = tid >> 6;
    const int lane = tid & 63;
    const int wm   = (wave >> 1) << 6;
    const int wn   = (wave & 1) << 6;
    const int l16  = lane & 15;
    const int quad = lane >> 4;
    const int rk   = l16 & 7;

    int aoff[4], boff[4], loff[4];
    #pragma unroll
    for (int p = 0; p < 4; ++p) {
        int L   = p * 256 + wave * 64 + lane;
        int row = L >> 3;
        int swz = (L & 7) ^ (row & 7);
        aoff[p] = (bm + row) * lda + swz * 8;
        boff[p] = (bn + row) * ldb + swz * 8;
        loff[p] = L * 8;
    }

    // prologue: stage K-tile 0 into buffer 0
    #pragma unroll
    for (int p = 0; p < 4; ++p) g2l16(A + aoff[p], As + loff[p]);
    #pragma unroll
    for (int p = 0; p < 4; ++p) g2l16(B + boff[p], Bs + loff[p]);
    __syncthreads();

    int cur = 0;
    for (int k0 = 0; k0 < K; k0 += 64) {
        const int nxt = cur ^ 1;
        if (k0 + 64 < K) {
            #pragma unroll
            for (int p = 0; p < 4; ++p)
                g2l16(A + aoff[p] + k0 + 64, As + nxt * 8192 + loff[p]);
            #pragma unroll
            for (int p = 0; p < 4; ++p)
                g2l16(B + boff[p] + k0 + 64, Bs + nxt * 8192 + loff[p]);
        }

        const short* Asc = As + cur * 8192;
        const short* Bsc = Bs + cur * 8192;
        #pragma unroll
        for (int h = 0; h < 2; ++h) {
            const int cs8 = ((((h << 2) | quad) ^ rk) << 3);
            bf16x8 b[4];
            #pragma unroll
            for (int nt = 0; nt < 4; ++nt)
                b[nt] = *(const bf16x8*)(Bsc + (wn + nt * 16 + l16) * 64 + cs8);
            #pragma unroll
            for (int mt = 0; mt < 4; ++mt) {
                bf16x8 a = *(const bf16x8*)(Asc + (wm + mt * 16 + l16) * 64 + cs8);
                #pragma unroll
                for (int nt = 0; nt < 4; ++nt)
                    acc[mt][nt] = __builtin_amdgcn_mfma_f32_16x16x32_bf16(
                        a, b[nt], acc[mt][nt], 0, 0, 0);
            }
        }
        __syncthreads();
        cur = nxt;
    }
}

__device__ __forceinline__ void store_tile_bf16(
    f32x4 (&acc)[4][4], short* __restrict__ C, int ldc, int bm, int bn)
{
    const int tid  = threadIdx.x;
    const int wave = tid >> 6;
    const int lane = tid & 63;
    const int wm   = (wave >> 1) << 6;
    const int wn   = (wave & 1) << 6;
    const int l16  = lane & 15;
    const int quad = lane >> 4;
    #pragma unroll
    for (int nt = 0; nt < 4; ++nt) {
        int col = bn + wn + nt * 16 + l16;
        #pragma unroll
        for (int mt = 0; mt < 4; ++mt) {
            int rowb = bm + wm + mt * 16 + quad * 4;
            #pragma unroll
            for (int r = 0; r < 4; ++r)
                C[(size_t)(rowb + r) * ldc + col] = f2bf(acc[mt][nt][r]);
        }
    }
}

// Fragment-layout store: 8 coalesced uint4 per thread.
__device__ __forceinline__ void store_frag(
    f32x4 (&acc)[4][4], short* __restrict__ planeTile)
{
    uint4* p = (uint4*)planeTile;
    const int tid = threadIdx.x;
    #pragma unroll
    for (int c = 0; c < 8; ++c) {
        int nt = c >> 1, mt0 = (c & 1) * 2;
        uint4 o = {pack2bf(acc[mt0][nt][0],     acc[mt0][nt][1]),
                   pack2bf(acc[mt0][nt][2],     acc[mt0][nt][3]),
                   pack2bf(acc[mt0 + 1][nt][0], acc[mt0 + 1][nt][1]),
                   pack2bf(acc[mt0 + 1][nt][2], acc[mt0 + 1][nt][3])};
        p[c * 256 + tid] = o;
    }
}

// Reduce one fragment chunk (tile, c) across SK planes -> row-major output.
template <bool OUT_F32>
__device__ __forceinline__ void reduce_unit(
    const short* __restrict__ P, size_t planeU4, int SK,
    int tile, int c, int tilesX, void* __restrict__ Out, int ldc,
    const float* __restrict__ bias)
{
    const int bm = (tile / tilesX) << 7;
    const int bn = (tile % tilesX) << 7;
    const int tid  = threadIdx.x;
    const int wave = tid >> 6;
    const int lane = tid & 63;
    const int wm   = (wave >> 1) << 6;
    const int wn   = (wave & 1) << 6;
    const int l16  = lane & 15;
    const int quad = lane >> 4;
    const int nt   = c >> 1, mt0 = (c & 1) * 2;

    const uint4* P4 = (const uint4*)P;
    const size_t base = (size_t)tile * 2048 + (size_t)c * 256 + tid;
    float f[8] = {0, 0, 0, 0, 0, 0, 0, 0};
    for (int z = 0; z < SK; ++z) {
        uint4 v = P4[(size_t)z * planeU4 + base];
        f[0] += bflo(v.x); f[1] += bfhi(v.x);
        f[2] += bflo(v.y); f[3] += bfhi(v.y);
        f[4] += bflo(v.z); f[5] += bfhi(v.z);
        f[6] += bflo(v.w); f[7] += bfhi(v.w);
    }
    const int col = bn + wn + nt * 16 + l16;
    float bv = 0.f;
    if (OUT_F32) bv = bias[col];
    #pragma unroll
    for (int j = 0; j < 8; ++j) {
        int mt  = mt0 + (j >> 2);
        int row = bm + wm + mt * 16 + quad * 4 + (j & 3);
        if (OUT_F32)
            ((float*)Out)[(size_t)row * ldc + col] = f[j] + bv;
        else
            ((short*)Out)[(size_t)row * ldc + col] = f2bf(f[j]);
    }
}

// ---------------------------------------------------------------------------
// Merged dispatch: blocks [0,512)   = folded stage-1 split-K GEMM (SK=4,
//                                     Kpart=512) -> s1 partial planes;
//                  blocks [512,1024)= W2 = B2 @ VcatT^T (1024x2048, K=2048,
//                                     SK=4, Kpart=512) -> W2 partial planes.
// The two halves are mutually independent (both depend only on aux), so one
// dispatch removes a kernel boundary + one GEMM fill/drain tail.
// ---------------------------------------------------------------------------
__global__ __launch_bounds__(256, 2) void gemm_s1w2(
    const short* __restrict__ xe, const short* __restrict__ xo,
    const short* __restrict__ B1f,
    const short* __restrict__ B2, const short* __restrict__ VcatT,
    short* __restrict__ P, short* __restrict__ PW)
{
    __shared__ __align__(16) short As[2 * 128 * 64];
    __shared__ __align__(16) short Bs[2 * 128 * 64];

    f32x4 acc[4][4];
    #pragma unroll
    for (int i = 0; i < 4; ++i)
        #pragma unroll
        for (int j = 0; j < 4; ++j)
            acc[i][j] = (f32x4){0.f, 0.f, 0.f, 0.f};

    const int raw = (int)blockIdx.x;
    if (raw < 512) {
        const int u    = xcd_swizzle(raw, 512);
        const int z    = u >> 7;          // SK = 4
        const int tile = u & 127;         // 8 x 16 tiles
        const int tx   = tile & 15, ty = tile >> 4;
        const bool odd = (tx & 8) != 0;
        const short* A = (odd ? xo : xe) + (size_t)z * 512;
        const short* B = B1f + (odd ? (size_t)1024 * 2048 : 0) + (size_t)z * 512;
        const int bm   = ty << 7;
        const int bn   = (tx & 7) << 7;

        tile_core(A, 2048, B, 2048, 512, As, Bs, bm, bn, acc);
        store_frag(acc, P + (size_t)z * 2097152 + (size_t)tile * 16384);
    } else {
        const int u    = xcd_swizzle(raw - 512, 512);
        const int z    = u >> 7;          // SK = 4
        const int tile = u & 127;         // 8(p) x 16(f) tiles
        const int bm   = (tile >> 4) << 7;
        const int bn   = (tile & 15) << 7;

        tile_core(B2 + (size_t)z * 512, 2048, VcatT + (size_t)z * 512, 2048,
                  512, As, Bs, bm, bn, acc);
        store_frag(acc, PW + (size_t)z * 2097152 + (size_t)tile * 16384);
    }
}

// Merged reduce: blocks [0,1024) -> Xp from P; [1024,2048) -> W2 from PW.
// Both halves: 128 tiles x 8 chunks, tilesX=16, SK=4, bf16 out, ldc 2048.
__global__ __launch_bounds__(256) void reduce_s1w2(
    const short* __restrict__ P, const short* __restrict__ PW,
    short* __restrict__ Xp, short* __restrict__ W2)
{
    const int b   = (int)blockIdx.x;
    const int sub = b & 1023;
    if (b < 1024)
        reduce_unit<false>(P,  (size_t)2097152 >> 3, 4, sub >> 3, sub & 7,
                           16, Xp, 2048, nullptr);
    else
        reduce_unit<false>(PW, (size_t)2097152 >> 3, 4, sub >> 3, sub & 7,
                           16, W2, 2048, nullptr);
}

// ---------------------------------------------------------------------------
// Generic split-K GEMM into fragment-layout bf16 partial planes.
// ---------------------------------------------------------------------------
__global__ __launch_bounds__(256, 2) void gemm_sk_frag(
    const short* __restrict__ A, int lda,
    const short* __restrict__ B, int ldb,
    short* __restrict__ P, size_t planeShorts, int Kpart,
    int tileShift, int tilesXShift)
{
    __shared__ __align__(16) short As[2 * 128 * 64];
    __shared__ __align__(16) short Bs[2 * 128 * 64];

    f32x4 acc[4][4];
    #pragma unroll
    for (int i = 0; i < 4; ++i)
        #pragma unroll
        for (int j = 0; j < 4; ++j)
            acc[i][j] = (f32x4){0.f, 0.f, 0.f, 0.f};

    const int u    = xcd_swizzle((int)blockIdx.x, (int)gridDim.x);
    const int z    = u >> tileShift;
    const int tile = u & ((1 << tileShift) - 1);
    const int bm   = (tile >> tilesXShift) << 7;
    const int bn   = (tile & ((1 << tilesXShift) - 1)) << 7;

    tile_core(A + (size_t)z * Kpart, lda, B + (size_t)z * Kpart, ldb, Kpart,
              As, Bs, bm, bn, acc);
    store_frag(acc, P + (size_t)z * planeShorts + (size_t)tile * 16384);
}

template <bool OUT_F32>
__global__ __launch_bounds__(256) void reduce_frag(
    const short* __restrict__ P, size_t planeShorts, int SK,
    int tilesX, void* __restrict__ Out, int ldc,
    const float* __restrict__ bias)
{
    reduce_unit<OUT_F32>(P, planeShorts >> 3, SK,
                         (int)(blockIdx.x >> 3), (int)(blockIdx.x & 7),
                         tilesX, Out, ldc, bias);
}

// ---------------------------------------------------------------------------
// Direct GEMM for the small-ws fallback path
// ---------------------------------------------------------------------------
template <bool OUT_F32>
__global__ __launch_bounds__(256, 2) void gemm_direct(
    const short* __restrict__ A, int lda,
    const short* __restrict__ B, int ldb,
    void* __restrict__ Cv, int ldc,
    const float* __restrict__ bias, int K)
{
    __shared__ __align__(16) short As[2 * 128 * 64];
    __shared__ __align__(16) short Bs[2 * 128 * 64];

    f32x4 acc[4][4];
    #pragma unroll
    for (int i = 0; i < 4; ++i)
        #pragma unroll
        for (int j = 0; j < 4; ++j)
            acc[i][j] = (f32x4){0.f, 0.f, 0.f, 0.f};

    const int bm = blockIdx.y << 7;
    const int bn = blockIdx.x << 7;
    tile_core(A, lda, B, ldb, K, As, Bs, bm, bn, acc);

    const int tid  = threadIdx.x;
    const int wave = tid >> 6;
    const int lane = tid & 63;
    const int wm   = (wave >> 1) << 6;
    const int wn   = (wave & 1) << 6;
    const int l16  = lane & 15;
    const int quad = lane >> 4;

    if (OUT_F32) {
        float* C = (float*)Cv;
        #pragma unroll
        for (int nt = 0; nt < 4; ++nt) {
            int col = bn + wn + nt * 16 + l16;
            float bv = bias ? bias[col] : 0.f;
            #pragma unroll
            for (int mt = 0; mt < 4; ++mt) {
                int rowb = bm + wm + mt * 16 + quad * 4;
                #pragma unroll
                for (int r = 0; r < 4; ++r)
                    C[(size_t)(rowb + r) * ldc + col] = acc[mt][nt][r] + bv;
            }
        }
    } else {
        store_tile_bf16(acc, (short*)Cv, ldc, bm, bn);
    }
}

// Fallback stage-1 (full K), 128 blocks.
__global__ __launch_bounds__(256, 2) void gemm_s1f_dir(
    const short* __restrict__ xe, const short* __restrict__ xo,
    const short* __restrict__ B1f, short* __restrict__ Xp)
{
    __shared__ __align__(16) short As[2 * 128 * 64];
    __shared__ __align__(16) short Bs[2 * 128 * 64];

    f32x4 acc[4][4];
    #pragma unroll
    for (int i = 0; i < 4; ++i)
        #pragma unroll
        for (int j = 0; j < 4; ++j)
            acc[i][j] = (f32x4){0.f, 0.f, 0.f, 0.f};

    const int u    = (int)blockIdx.x;
    const int tx   = u & 15, ty = u >> 4;
    const bool odd = (tx & 8) != 0;
    const short* A = odd ? xo : xe;
    const short* B = B1f + (odd ? (size_t)1024 * 2048 : 0);
    const int bm   = ty << 7;
    const int bn   = (tx & 7) << 7;

    tile_core(A, 2048, B, 2048, 2048, As, Bs, bm, bn, acc);
    store_tile_bf16(acc, Xp, 2048, bm, bn + (odd ? 1024 : 0));
}

extern "C" void kernel_launch(void* const* d_in, const int* in_sizes, int n_in,
                              void* d_out, int out_size, void* d_ws, size_t ws_size,
                              hipStream_t stream) {
    const float* x    = (const float*)d_in[0];
    const float* Ur   = (const float*)d_in[1];
    const float* Ui   = (const float*)d_in[2];
    const float* S    = (const float*)d_in[3];
    const float* Vr   = (const float*)d_in[4];
    const float* Vi   = (const float*)d_in[5];
    const float* bias = (const float*)d_in[6];
    float* out = (float*)d_out;

    short* ws    = (short*)d_ws;
    short* xe    = ws;                                  // 1024*2048
    short* xo    = xe    + (size_t)1024 * 2048;         // 1024*2048
    short* B1f   = xo    + (size_t)1024 * 2048;         // 2048*2048
    short* VcatT = B1f   + (size_t)2048 * 2048;         // 2048*2048
    short* B2    = VcatT + (size_t)2048 * 2048;         // 1024*2048
    short* Ucat  = B2    + (size_t)1024 * 2048;         // 4096*1024
    short* Xp    = Ucat  + (size_t)4096 * 1024;         // 1024*2048
    short* W2    = Xp    + (size_t)1024 * 2048;         // 1024*2048
    short* Gm    = W2    + (size_t)1024 * 2048;         // 1024*1024
    short* Pp    = Gm    + (size_t)1024 * 1024;         // partials 8.39M shorts
    short* PW    = Pp    + (size_t)8388608;             // W2 partials 8.39M

    const size_t need = (size_t)((char*)(PW + (size_t)8388608) - (char*)d_ws);

    aux_all8<<<dim3(8192), 256, 0, stream>>>(
        x, Ur, Ui, S, Vr, Vi, xe, xo, B1f, VcatT, B2, Ucat);

    if (ws_size >= need) {
        // [s1 || W2] merged (1024 blocks, both SK=4 Kpart=512)
        gemm_s1w2<<<dim3(1024), 256, 0, stream>>>(
            xe, xo, B1f, B2, VcatT, Pp, PW);
        reduce_s1w2<<<dim3(2048), 256, 0, stream>>>(Pp, PW, Xp, W2);

        // G = Xp @ W2^T (1024x1024, K=2048; SK=8, Kpart=256, 512 blocks)
        gemm_sk_frag<<<dim3(512), 256, 0, stream>>>(
            Xp, 2048, W2, 2048, Pp, (size_t)1048576, 256, 6, 3);
        reduce_frag<false><<<dim3(512), 256, 0, stream>>>(
            Pp, (size_t)1048576, 8, 8, Gm, 1024, nullptr);

        // out = G @ Ucat^T + bias (1024x4096, K=1024; SK=2, Kpart=512)
        gemm_sk_frag<<<dim3(512), 256, 0, stream>>>(
            Gm, 1024, Ucat, 1024, Pp, (size_t)4194304, 512, 8, 5);
        reduce_frag<true><<<dim3(2048), 256, 0, stream>>>(
            Pp, (size_t)4194304, 2, 32, out, 4096, bias);
    } else {
        gemm_s1f_dir<<<dim3(128), 256, 0, stream>>>(xe, xo, B1f, Xp);
        gemm_direct<false><<<dim3(16, 8), 256, 0, stream>>>(
            B2, 2048, VcatT, 2048, W2, 2048, nullptr, 2048);
        gemm_direct<false><<<dim3(8, 8), 256, 0, stream>>>(
            Xp, 2048, W2, 2048, Gm, 1024, nullptr, 2048);
        gemm_direct<true><<<dim3(32, 8), 256, 0, stream>>>(
            Gm, 1024, Ucat, 1024, out, 4096, bias, 1024);
    }
}

// Round 9
// 169.739 us; speedup vs baseline: 1.3219x; 1.3219x over previous
//
#include <hip/hip_runtime.h>
#include <math.h>
#include <stdint.h>

#define PI2 6.28318530717958647692f

typedef __bf16 bf16x8 __attribute__((ext_vector_type(8)));
typedef float f32x4 __attribute__((ext_vector_type(4)));

typedef __attribute__((address_space(1))) const void gvoid_t;
typedef __attribute__((address_space(3))) void lvoid_t;

__device__ __forceinline__ void g2l16(const void* g, void* l) {
    __builtin_amdgcn_global_load_lds(
        reinterpret_cast<gvoid_t*>(reinterpret_cast<uintptr_t>(g)),
        reinterpret_cast<lvoid_t*>(reinterpret_cast<uintptr_t>(l)),
        16, 0, 0);
}

__device__ __forceinline__ short f2bf(float f) {
    unsigned u = __float_as_uint(f);
    u += 0x7FFFu + ((u >> 16) & 1u);          // round-to-nearest-even
    return (short)(u >> 16);
}

__device__ __forceinline__ unsigned pack2bf(float a, float b) {
    return (unsigned)(unsigned short)f2bf(a) |
           ((unsigned)(unsigned short)f2bf(b) << 16);
}

__device__ __forceinline__ float bflo(unsigned v) { return __uint_as_float(v << 16); }
__device__ __forceinline__ float bfhi(unsigned v) { return __uint_as_float(v & 0xFFFF0000u); }

// XCD-locality swizzle (G must be a multiple of 8 -> bijective).
__device__ __forceinline__ int xcd_swizzle(int blk, int G) {
    return (blk & 7) * (G >> 3) + (blk >> 3);
}

// ---------------------------------------------------------------------------
// Fused aux kernel, block-range dispatch, 7168 blocks:
//   [0,   1024): xe/xo radix-2 fold of x (1024x2048 each, bf16)
//   [1024,3072): B1f folded DFT basis (2048x2048)
//   [3072,4096): VcatT via LDS-TILED TRANSPOSE (R8's strided gather was a
//                14x over-fetch: 224 MB FETCH for 16 MB of V). 64x64 f32
//                tile per block, coalesced row loads, lds[64][68] staging,
//                bf16-packed row writes. VcatT[f][kk] = V?[kk][col(f)],
//                f = (col&1)*1024 + m*512 + (col>>1), m: 0=Vr 1=Vi.
//   [4096,5120): B2 (1024x2048), B2[p][k] = basis_p(k) * S[k]
//   [5120,7168): Ucat (4096x1024) = [Ur | Ui]
// ---------------------------------------------------------------------------
__global__ __launch_bounds__(256) void aux_all8(
    const float* __restrict__ x,
    const float* __restrict__ Ur, const float* __restrict__ Ui,
    const float* __restrict__ S,
    const float* __restrict__ Vr, const float* __restrict__ Vi,
    short* __restrict__ xe, short* __restrict__ xo,
    short* __restrict__ B1f, short* __restrict__ VcatT,
    short* __restrict__ B2, short* __restrict__ Ucat)
{
    __shared__ float tlds[64][68];   // 17.4 KB; 8 blocks/CU still fits 160 KB
    const int b   = (int)blockIdx.x;
    const int tid = threadIdx.x;

    if (b < 1024) {
        // radix-2 fold: xe = x[:, :2048] + x[:, 2048:], xo = difference
        unsigned i = (b * 256u + tid) * 8u;
        int r = i >> 11, j0 = i & 2047;
        const float* xr = x + (size_t)r * 4096 + j0;
        float4 a0 = ((const float4*)xr)[0], a1 = ((const float4*)xr)[1];
        float4 b0 = ((const float4*)(xr + 2048))[0],
               b1 = ((const float4*)(xr + 2048))[1];
        uint4 oe = {pack2bf(a0.x + b0.x, a0.y + b0.y),
                    pack2bf(a0.z + b0.z, a0.w + b0.w),
                    pack2bf(a1.x + b1.x, a1.y + b1.y),
                    pack2bf(a1.z + b1.z, a1.w + b1.w)};
        *(uint4*)(xe + i) = oe;
        uint4 oo = {pack2bf(a0.x - b0.x, a0.y - b0.y),
                    pack2bf(a0.z - b0.z, a0.w - b0.w),
                    pack2bf(a1.x - b1.x, a1.y - b1.y),
                    pack2bf(a1.z - b1.z, a1.w - b1.w)};
        *(uint4*)(xo + i) = oo;
    } else if (b < 3072) {
        unsigned i = ((b - 1024) * 256u + tid) * 8u;
        int r = i >> 11, j0 = i & 2047;
        const float inv_n = 1.0f / 4096.0f;
        float v[8];
        if (r < 512) {
            if (r == 0) {
                #pragma unroll
                for (int u = 0; u < 8; ++u) v[u] = inv_n;
            } else {
                #pragma unroll
                for (int u = 0; u < 8; ++u) {
                    int t = (r * (j0 + u)) & 2047;
                    v[u] = 2.0f * inv_n * cosf((float)t * (PI2 / 2048.0f));
                }
            }
        } else if (r < 1024) {
            int m = r - 512;
            #pragma unroll
            for (int u = 0; u < 8; ++u) {
                int t = (m * (j0 + u)) & 2047;
                v[u] = -2.0f * inv_n * sinf((float)t * (PI2 / 2048.0f));
            }
        } else if (r < 1536) {
            int c = 2 * (r - 1024) + 1;
            #pragma unroll
            for (int u = 0; u < 8; ++u) {
                int t = (c * (j0 + u)) & 4095;
                v[u] = 2.0f * inv_n * cosf((float)t * (PI2 / 4096.0f));
            }
        } else {
            int m = 2 * (r - 1536) + 1;
            #pragma unroll
            for (int u = 0; u < 8; ++u) {
                int t = (m * (j0 + u)) & 4095;
                v[u] = -2.0f * inv_n * sinf((float)t * (PI2 / 4096.0f));
            }
        }
        uint4 o = {pack2bf(v[0], v[1]), pack2bf(v[2], v[3]),
                   pack2bf(v[4], v[5]), pack2bf(v[6], v[7])};
        *(uint4*)(B1f + i) = o;
    } else if (b < 4096) {
        // LDS-tiled V transpose: 512 tiles per matrix (32 kk-tiles x 16 c-tiles)
        const int bb  = b - 3072;
        const int m   = bb >> 9;           // 0 = Vr, 1 = Vi
        const int tt  = bb & 511;
        const int tkk = tt >> 4;           // kk tile 0..31
        const int tc  = tt & 15;           // c  tile 0..15
        const float* src = (m ? Vi : Vr) + (size_t)(tkk * 64) * 1024 + tc * 64;

        #pragma unroll
        for (int pass = 0; pass < 4; ++pass) {
            int r  = pass * 16 + (tid >> 4);        // 0..63
            int cq = (tid & 15) * 4;                // 0..60
            float4 v = *(const float4*)(src + (size_t)r * 1024 + cq);
            *(float4*)&tlds[r][cq] = v;             // 68-stride: 16B-aligned
        }
        __syncthreads();

        const int cl = tid & 63;                    // local col -> f row
        const int ch = (tid >> 6) * 16;             // kk chunk
        const int c  = tc * 64 + cl;
        const int f  = ((c & 1) << 10) + (m << 9) + (c >> 1);
        float vv[16];
        #pragma unroll
        for (int j = 0; j < 16; ++j) vv[j] = tlds[ch + j][cl];
        uint4 o0 = {pack2bf(vv[0],  vv[1]),  pack2bf(vv[2],  vv[3]),
                    pack2bf(vv[4],  vv[5]),  pack2bf(vv[6],  vv[7])};
        uint4 o1 = {pack2bf(vv[8],  vv[9]),  pack2bf(vv[10], vv[11]),
                    pack2bf(vv[12], vv[13]), pack2bf(vv[14], vv[15])};
        uint4* dst = (uint4*)(VcatT + (size_t)f * 2048 + tkk * 64 + ch);
        dst[0] = o0;
        dst[1] = o1;
    } else if (b < 5120) {
        // B2[p][k] = basis_p(k) * S[k], p-major (1024 x 2048)
        unsigned i = ((b - 4096) * 256u + tid) * 8u;
        int p = i >> 11, k0 = i & 2047;
        float4 s0 = *(const float4*)(S + k0);
        float4 s1 = *(const float4*)(S + k0 + 4);
        float sv[8] = {s0.x, s0.y, s0.z, s0.w, s1.x, s1.y, s1.z, s1.w};
        const float inv_n = 1.0f / 2048.0f;
        float v[8];
        if (p == 0) {
            #pragma unroll
            for (int u = 0; u < 8; ++u) v[u] = inv_n * sv[u];
        } else if (p < 512) {
            #pragma unroll
            for (int u = 0; u < 8; ++u) {
                int t = (p * (k0 + u)) & 2047;
                v[u] = 2.0f * inv_n * cosf((float)t * (PI2 / 2048.0f)) * sv[u];
            }
        } else {
            int q = p - 512;
            #pragma unroll
            for (int u = 0; u < 8; ++u) {
                int t = (q * (k0 + u)) & 2047;
                v[u] = -2.0f * inv_n * sinf((float)t * (PI2 / 2048.0f)) * sv[u];
            }
        }
        uint4 o = {pack2bf(v[0], v[1]), pack2bf(v[2], v[3]),
                   pack2bf(v[4], v[5]), pack2bf(v[6], v[7])};
        *(uint4*)(B2 + i) = o;
    } else {
        unsigned i = ((b - 5120) * 256u + tid) * 8u;
        int o_ = i >> 10, c = i & 1023;
        const float* src = (c < 512) ? (Ur + (size_t)o_ * 512 + c)
                                     : (Ui + (size_t)o_ * 512 + (c - 512));
        float4 a = ((const float4*)src)[0], bq = ((const float4*)src)[1];
        uint4 o = {pack2bf(a.x, a.y), pack2bf(a.z, a.w),
                   pack2bf(bq.x, bq.y), pack2bf(bq.z, bq.w)};
        *(uint4*)(Ucat + i) = o;
    }
}

// ---------------------------------------------------------------------------
// 128x128 MFMA tile core, BK=64, XOR-swizzled LDS, double-buffered
// (round-5 proven): next K-tile's global_load_lds issues BEFORE the compute
// phase; one __syncthreads() per K-step. LDS 64 KB/block -> 2 blocks/CU.
// ---------------------------------------------------------------------------
__device__ __forceinline__ void tile_core(
    const short* __restrict__ A, int lda,
    const short* __restrict__ B, int ldb, int K,
    short* As, short* Bs, int bm, int bn, f32x4 (&acc)[4][4])
{
    const int tid  = threadIdx.x;
    const int wave = tid >> 6;
    const int lane = tid & 63;
    const int wm   = (wave >> 1) << 6;
    const int wn   = (wave & 1) << 6;
    const int l16  = lane & 15;
    const int quad = lane >> 4;
    const int rk   = l16 & 7;

    int aoff[4], boff[4], loff[4];
    #pragma unroll
    for (int p = 0; p < 4; ++p) {
        int L   = p * 256 + wave * 64 + lane;
        int row = L >> 3;
        int swz = (L & 7) ^ (row & 7);
        aoff[p] = (bm + row) * lda + swz * 8;
        boff[p] = (bn + row) * ldb + swz * 8;
        loff[p] = L * 8;
    }

    // prologue: stage K-tile 0 into buffer 0
    #pragma unroll
    for (int p = 0; p < 4; ++p) g2l16(A + aoff[p], As + loff[p]);
    #pragma unroll
    for (int p = 0; p < 4; ++p) g2l16(B + boff[p], Bs + loff[p]);
    __syncthreads();

    int cur = 0;
    for (int k0 = 0; k0 < K; k0 += 64) {
        const int nxt = cur ^ 1;
        if (k0 + 64 < K) {
            #pragma unroll
            for (int p = 0; p < 4; ++p)
                g2l16(A + aoff[p] + k0 + 64, As + nxt * 8192 + loff[p]);
            #pragma unroll
            for (int p = 0; p < 4; ++p)
                g2l16(B + boff[p] + k0 + 64, Bs + nxt * 8192 + loff[p]);
        }

        const short* Asc = As + cur * 8192;
        const short* Bsc = Bs + cur * 8192;
        #pragma unroll
        for (int h = 0; h < 2; ++h) {
            const int cs8 = ((((h << 2) | quad) ^ rk) << 3);
            bf16x8 b[4];
            #pragma unroll
            for (int nt = 0; nt < 4; ++nt)
                b[nt] = *(const bf16x8*)(Bsc + (wn + nt * 16 + l16) * 64 + cs8);
            #pragma unroll
            for (int mt = 0; mt < 4; ++mt) {
                bf16x8 a = *(const bf16x8*)(Asc + (wm + mt * 16 + l16) * 64 + cs8);
                #pragma unroll
                for (int nt = 0; nt < 4; ++nt)
                    acc[mt][nt] = __builtin_amdgcn_mfma_f32_16x16x32_bf16(
                        a, b[nt], acc[mt][nt], 0, 0, 0);
            }
        }
        __syncthreads();
        cur = nxt;
    }
}

__device__ __forceinline__ void store_tile_bf16(
    f32x4 (&acc)[4][4], short* __restrict__ C, int ldc, int bm, int bn)
{
    const int tid  = threadIdx.x;
    const int wave = tid >> 6;
    const int lane = tid & 63;
    const int wm   = (wave >> 1) << 6;
    const int wn   = (wave & 1) << 6;
    const int l16  = lane & 15;
    const int quad = lane >> 4;
    #pragma unroll
    for (int nt = 0; nt < 4; ++nt) {
        int col = bn + wn + nt * 16 + l16;
        #pragma unroll
        for (int mt = 0; mt < 4; ++mt) {
            int rowb = bm + wm + mt * 16 + quad * 4;
            #pragma unroll
            for (int r = 0; r < 4; ++r)
                C[(size_t)(rowb + r) * ldc + col] = f2bf(acc[mt][nt][r]);
        }
    }
}

// Fragment-layout store: 8 coalesced uint4 per thread.
__device__ __forceinline__ void store_frag(
    f32x4 (&acc)[4][4], short* __restrict__ planeTile)
{
    uint4* p = (uint4*)planeTile;
    const int tid = threadIdx.x;
    #pragma unroll
    for (int c = 0; c < 8; ++c) {
        int nt = c >> 1, mt0 = (c & 1) * 2;
        uint4 o = {pack2bf(acc[mt0][nt][0],     acc[mt0][nt][1]),
                   pack2bf(acc[mt0][nt][2],     acc[mt0][nt][3]),
                   pack2bf(acc[mt0 + 1][nt][0], acc[mt0 + 1][nt][1]),
                   pack2bf(acc[mt0 + 1][nt][2], acc[mt0 + 1][nt][3])};
        p[c * 256 + tid] = o;
    }
}

// Reduce one fragment chunk (tile, c) across SK planes -> row-major output.
template <bool OUT_F32>
__device__ __forceinline__ void reduce_unit(
    const short* __restrict__ P, size_t planeU4, int SK,
    int tile, int c, int tilesX, void* __restrict__ Out, int ldc,
    const float* __restrict__ bias)
{
    const int bm = (tile / tilesX) << 7;
    const int bn = (tile % tilesX) << 7;
    const int tid  = threadIdx.x;
    const int wave = tid >> 6;
    const int lane = tid & 63;
    const int wm   = (wave >> 1) << 6;
    const int wn   = (wave & 1) << 6;
    const int l16  = lane & 15;
    const int quad = lane >> 4;
    const int nt   = c >> 1, mt0 = (c & 1) * 2;

    const uint4* P4 = (const uint4*)P;
    const size_t base = (size_t)tile * 2048 + (size_t)c * 256 + tid;
    float f[8] = {0, 0, 0, 0, 0, 0, 0, 0};
    for (int z = 0; z < SK; ++z) {
        uint4 v = P4[(size_t)z * planeU4 + base];
        f[0] += bflo(v.x); f[1] += bfhi(v.x);
        f[2] += bflo(v.y); f[3] += bfhi(v.y);
        f[4] += bflo(v.z); f[5] += bfhi(v.z);
        f[6] += bflo(v.w); f[7] += bfhi(v.w);
    }
    const int col = bn + wn + nt * 16 + l16;
    float bv = 0.f;
    if (OUT_F32) bv = bias[col];
    #pragma unroll
    for (int j = 0; j < 8; ++j) {
        int mt  = mt0 + (j >> 2);
        int row = bm + wm + mt * 16 + quad * 4 + (j & 3);
        if (OUT_F32)
            ((float*)Out)[(size_t)row * ldc + col] = f[j] + bv;
        else
            ((short*)Out)[(size_t)row * ldc + col] = f2bf(f[j]);
    }
}

// ---------------------------------------------------------------------------
// Merged dispatch: blocks [0,512)   = folded stage-1 split-K GEMM (SK=4,
//                                     Kpart=512) -> s1 partial planes;
//                  blocks [512,1024)= W2 = B2 @ VcatT^T (1024x2048, K=2048,
//                                     SK=4, Kpart=512) -> W2 partial planes.
// ---------------------------------------------------------------------------
__global__ __launch_bounds__(256, 2) void gemm_s1w2(
    const short* __restrict__ xe, const short* __restrict__ xo,
    const short* __restrict__ B1f,
    const short* __restrict__ B2, const short* __restrict__ VcatT,
    short* __restrict__ P, short* __restrict__ PW)
{
    __shared__ __align__(16) short As[2 * 128 * 64];
    __shared__ __align__(16) short Bs[2 * 128 * 64];

    f32x4 acc[4][4];
    #pragma unroll
    for (int i = 0; i < 4; ++i)
        #pragma unroll
        for (int j = 0; j < 4; ++j)
            acc[i][j] = (f32x4){0.f, 0.f, 0.f, 0.f};

    const int raw = (int)blockIdx.x;
    if (raw < 512) {
        const int u    = xcd_swizzle(raw, 512);
        const int z    = u >> 7;          // SK = 4
        const int tile = u & 127;         // 8 x 16 tiles
        const int tx   = tile & 15, ty = tile >> 4;
        const bool odd = (tx & 8) != 0;
        const short* A = (odd ? xo : xe) + (size_t)z * 512;
        const short* B = B1f + (odd ? (size_t)1024 * 2048 : 0) + (size_t)z * 512;
        const int bm   = ty << 7;
        const int bn   = (tx & 7) << 7;

        tile_core(A, 2048, B, 2048, 512, As, Bs, bm, bn, acc);
        store_frag(acc, P + (size_t)z * 2097152 + (size_t)tile * 16384);
    } else {
        const int u    = xcd_swizzle(raw - 512, 512);
        const int z    = u >> 7;          // SK = 4
        const int tile = u & 127;         // 8(p) x 16(f) tiles
        const int bm   = (tile >> 4) << 7;
        const int bn   = (tile & 15) << 7;

        tile_core(B2 + (size_t)z * 512, 2048, VcatT + (size_t)z * 512, 2048,
                  512, As, Bs, bm, bn, acc);
        store_frag(acc, PW + (size_t)z * 2097152 + (size_t)tile * 16384);
    }
}

// Merged reduce: blocks [0,1024) -> Xp from P; [1024,2048) -> W2 from PW.
__global__ __launch_bounds__(256) void reduce_s1w2(
    const short* __restrict__ P, const short* __restrict__ PW,
    short* __restrict__ Xp, short* __restrict__ W2)
{
    const int b   = (int)blockIdx.x;
    const int sub = b & 1023;
    if (b < 1024)
        reduce_unit<false>(P,  (size_t)2097152 >> 3, 4, sub >> 3, sub & 7,
                           16, Xp, 2048, nullptr);
    else
        reduce_unit<false>(PW, (size_t)2097152 >> 3, 4, sub >> 3, sub & 7,
                           16, W2, 2048, nullptr);
}

// ---------------------------------------------------------------------------
// Generic split-K GEMM into fragment-layout bf16 partial planes.
// ---------------------------------------------------------------------------
__global__ __launch_bounds__(256, 2) void gemm_sk_frag(
    const short* __restrict__ A, int lda,
    const short* __restrict__ B, int ldb,
    short* __restrict__ P, size_t planeShorts, int Kpart,
    int tileShift, int tilesXShift)
{
    __shared__ __align__(16) short As[2 * 128 * 64];
    __shared__ __align__(16) short Bs[2 * 128 * 64];

    f32x4 acc[4][4];
    #pragma unroll
    for (int i = 0; i < 4; ++i)
        #pragma unroll
        for (int j = 0; j < 4; ++j)
            acc[i][j] = (f32x4){0.f, 0.f, 0.f, 0.f};

    const int u    = xcd_swizzle((int)blockIdx.x, (int)gridDim.x);
    const int z    = u >> tileShift;
    const int tile = u & ((1 << tileShift) - 1);
    const int bm   = (tile >> tilesXShift) << 7;
    const int bn   = (tile & ((1 << tilesXShift) - 1)) << 7;

    tile_core(A + (size_t)z * Kpart, lda, B + (size_t)z * Kpart, ldb, Kpart,
              As, Bs, bm, bn, acc);
    store_frag(acc, P + (size_t)z * planeShorts + (size_t)tile * 16384);
}

template <bool OUT_F32>
__global__ __launch_bounds__(256) void reduce_frag(
    const short* __restrict__ P, size_t planeShorts, int SK,
    int tilesX, void* __restrict__ Out, int ldc,
    const float* __restrict__ bias)
{
    reduce_unit<OUT_F32>(P, planeShorts >> 3, SK,
                         (int)(blockIdx.x >> 3), (int)(blockIdx.x & 7),
                         tilesX, Out, ldc, bias);
}

// ---------------------------------------------------------------------------
// Direct GEMM for the small-ws fallback path
// ---------------------------------------------------------------------------
template <bool OUT_F32>
__global__ __launch_bounds__(256, 2) void gemm_direct(
    const short* __restrict__ A, int lda,
    const short* __restrict__ B, int ldb,
    void* __restrict__ Cv, int ldc,
    const float* __restrict__ bias, int K)
{
    __shared__ __align__(16) short As[2 * 128 * 64];
    __shared__ __align__(16) short Bs[2 * 128 * 64];

    f32x4 acc[4][4];
    #pragma unroll
    for (int i = 0; i < 4; ++i)
        #pragma unroll
        for (int j = 0; j < 4; ++j)
            acc[i][j] = (f32x4){0.f, 0.f, 0.f, 0.f};

    const int bm = blockIdx.y << 7;
    const int bn = blockIdx.x << 7;
    tile_core(A, lda, B, ldb, K, As, Bs, bm, bn, acc);

    const int tid  = threadIdx.x;
    const int wave = tid >> 6;
    const int lane = tid & 63;
    const int wm   = (wave >> 1) << 6;
    const int wn   = (wave & 1) << 6;
    const int l16  = lane & 15;
    const int quad = lane >> 4;

    if (OUT_F32) {
        float* C = (float*)Cv;
        #pragma unroll
        for (int nt = 0; nt < 4; ++nt) {
            int col = bn + wn + nt * 16 + l16;
            float bv = bias ? bias[col] : 0.f;
            #pragma unroll
            for (int mt = 0; mt < 4; ++mt) {
                int rowb = bm + wm + mt * 16 + quad * 4;
                #pragma unroll
                for (int r = 0; r < 4; ++r)
                    C[(size_t)(rowb + r) * ldc + col] = acc[mt][nt][r] + bv;
            }
        }
    } else {
        store_tile_bf16(acc, (short*)Cv, ldc, bm, bn);
    }
}

// Fallback stage-1 (full K), 128 blocks.
__global__ __launch_bounds__(256, 2) void gemm_s1f_dir(
    const short* __restrict__ xe, const short* __restrict__ xo,
    const short* __restrict__ B1f, short* __restrict__ Xp)
{
    __shared__ __align__(16) short As[2 * 128 * 64];
    __shared__ __align__(16) short Bs[2 * 128 * 64];

    f32x4 acc[4][4];
    #pragma unroll
    for (int i = 0; i < 4; ++i)
        #pragma unroll
        for (int j = 0; j < 4; ++j)
            acc[i][j] = (f32x4){0.f, 0.f, 0.f, 0.f};

    const int u    = (int)blockIdx.x;
    const int tx   = u & 15, ty = u >> 4;
    const bool odd = (tx & 8) != 0;
    const short* A = odd ? xo : xe;
    const short* B = B1f + (odd ? (size_t)1024 * 2048 : 0);
    const int bm   = ty << 7;
    const int bn   = (tx & 7) << 7;

    tile_core(A, 2048, B, 2048, 2048, As, Bs, bm, bn, acc);
    store_tile_bf16(acc, Xp, 2048, bm, bn + (odd ? 1024 : 0));
}

extern "C" void kernel_launch(void* const* d_in, const int* in_sizes, int n_in,
                              void* d_out, int out_size, void* d_ws, size_t ws_size,
                              hipStream_t stream) {
    const float* x    = (const float*)d_in[0];
    const float* Ur   = (const float*)d_in[1];
    const float* Ui   = (const float*)d_in[2];
    const float* S    = (const float*)d_in[3];
    const float* Vr   = (const float*)d_in[4];
    const float* Vi   = (const float*)d_in[5];
    const float* bias = (const float*)d_in[6];
    float* out = (float*)d_out;

    short* ws    = (short*)d_ws;
    short* xe    = ws;                                  // 1024*2048
    short* xo    = xe    + (size_t)1024 * 2048;         // 1024*2048
    short* B1f   = xo    + (size_t)1024 * 2048;         // 2048*2048
    short* VcatT = B1f   + (size_t)2048 * 2048;         // 2048*2048
    short* B2    = VcatT + (size_t)2048 * 2048;         // 1024*2048
    short* Ucat  = B2    + (size_t)1024 * 2048;         // 4096*1024
    short* Xp    = Ucat  + (size_t)4096 * 1024;         // 1024*2048
    short* W2    = Xp    + (size_t)1024 * 2048;         // 1024*2048
    short* Gm    = W2    + (size_t)1024 * 2048;         // 1024*1024
    short* Pp    = Gm    + (size_t)1024 * 1024;         // partials 8.39M shorts
    short* PW    = Pp    + (size_t)8388608;             // W2 partials 8.39M

    const size_t need = (size_t)((char*)(PW + (size_t)8388608) - (char*)d_ws);

    aux_all8<<<dim3(7168), 256, 0, stream>>>(
        x, Ur, Ui, S, Vr, Vi, xe, xo, B1f, VcatT, B2, Ucat);

    if (ws_size >= need) {
        // [s1 || W2] merged (1024 blocks, both SK=4 Kpart=512)
        gemm_s1w2<<<dim3(1024), 256, 0, stream>>>(
            xe, xo, B1f, B2, VcatT, Pp, PW);
        reduce_s1w2<<<dim3(2048), 256, 0, stream>>>(Pp, PW, Xp, W2);

        // G = Xp @ W2^T (1024x1024, K=2048; SK=8, Kpart=256, 512 blocks)
        gemm_sk_frag<<<dim3(512), 256, 0, stream>>>(
            Xp, 2048, W2, 2048, Pp, (size_t)1048576, 256, 6, 3);
        reduce_frag<false><<<dim3(512), 256, 0, stream>>>(
            Pp, (size_t)1048576, 8, 8, Gm, 1024, nullptr);

        // out = G @ Ucat^T + bias (1024x4096, K=1024; SK=2, Kpart=512)
        gemm_sk_frag<<<dim3(512), 256, 0, stream>>>(
            Gm, 1024, Ucat, 1024, Pp, (size_t)4194304, 512, 8, 5);
        reduce_frag<true><<<dim3(2048), 256, 0, stream>>>(
            Pp, (size_t)4194304, 2, 32, out, 4096, bias);
    } else {
        gemm_s1f_dir<<<dim3(128), 256, 0, stream>>>(xe, xo, B1f, Xp);
        gemm_direct<false><<<dim3(16, 8), 256, 0, stream>>>(
            B2, 2048, VcatT, 2048, W2, 2048, nullptr, 2048);
        gemm_direct<false><<<dim3(8, 8), 256, 0, stream>>>(
            Xp, 2048, W2, 2048, Gm, 1024, nullptr, 2048);
        gemm_direct<true><<<dim3(32, 8), 256, 0, stream>>>(
            Gm, 1024, Ucat, 1024, out, 4096, bias, 1024);
    }
}

// Round 10
// 165.670 us; speedup vs baseline: 1.3544x; 1.0246x over previous
//
#include <hip/hip_runtime.h>
#include <math.h>
#include <stdint.h>

#define PI2 6.28318530717958647692f

typedef __bf16 bf16x8 __attribute__((ext_vector_type(8)));
typedef float f32x4 __attribute__((ext_vector_type(4)));

typedef __attribute__((address_space(1))) const void gvoid_t;
typedef __attribute__((address_space(3))) void lvoid_t;

__device__ __forceinline__ void g2l16(const void* g, void* l) {
    __builtin_amdgcn_global_load_lds(
        reinterpret_cast<gvoid_t*>(reinterpret_cast<uintptr_t>(g)),
        reinterpret_cast<lvoid_t*>(reinterpret_cast<uintptr_t>(l)),
        16, 0, 0);
}

__device__ __forceinline__ short f2bf(float f) {
    unsigned u = __float_as_uint(f);
    u += 0x7FFFu + ((u >> 16) & 1u);          // round-to-nearest-even
    return (short)(u >> 16);
}

__device__ __forceinline__ unsigned pack2bf(float a, float b) {
    return (unsigned)(unsigned short)f2bf(a) |
           ((unsigned)(unsigned short)f2bf(b) << 16);
}

__device__ __forceinline__ float bflo(unsigned v) { return __uint_as_float(v << 16); }
__device__ __forceinline__ float bfhi(unsigned v) { return __uint_as_float(v & 0xFFFF0000u); }

// XCD-locality swizzle (G must be a multiple of 8 -> bijective).
__device__ __forceinline__ int xcd_swizzle(int blk, int G) {
    return (blk & 7) * (G >> 3) + (blk >> 3);
}

// ---------------------------------------------------------------------------
// Fused aux kernel, block-range dispatch, 6144 blocks:
//   [0,   1024): xe/xo radix-2 fold of x (1024x2048 each, bf16)
//   [1024,3072): B1f folded DFT basis (2048x2048)
//   [3072,3584): VSe/VSo via LDS transpose + S-multiply + k-radix-2 fold:
//                VS[f][k] = S[k]*V?[k][col(f)];  VSe = VS[:, :1024]+VS[:,1024:],
//                VSo = difference. Each block: tile-pair (k, k+1024).
//   [3584,4096): B2' (1024x1024), frequency-parity row groups:
//                p'<256: cos F=2p'' | p'<512: sin F=2p'' |
//                p'<768: cos F=2p''+1 | else: sin F=2p''+1.  (no S here)
//   [4096,6144): Ucat (4096x1024) permuted to match B2' row order:
//                grp=c>>8: {Ur,Ui,Ur,Ui}[grp], src col = 2*(c&255)+(grp>>1).
// ---------------------------------------------------------------------------
__global__ __launch_bounds__(256) void aux_all8(
    const float* __restrict__ x,
    const float* __restrict__ Ur, const float* __restrict__ Ui,
    const float* __restrict__ S,
    const float* __restrict__ Vr, const float* __restrict__ Vi,
    short* __restrict__ xe, short* __restrict__ xo,
    short* __restrict__ B1f, short* __restrict__ VSe, short* __restrict__ VSo,
    short* __restrict__ B2, short* __restrict__ Ucat)
{
    __shared__ float tlds0[64][68];
    __shared__ float tlds1[64][68];
    __shared__ float s_lo[64], s_hi[64];
    const int b   = (int)blockIdx.x;
    const int tid = threadIdx.x;

    if (b < 1024) {
        // radix-2 fold: xe = x[:, :2048] + x[:, 2048:], xo = difference
        unsigned i = (b * 256u + tid) * 8u;
        int r = i >> 11, j0 = i & 2047;
        const float* xr = x + (size_t)r * 4096 + j0;
        float4 a0 = ((const float4*)xr)[0], a1 = ((const float4*)xr)[1];
        float4 b0 = ((const float4*)(xr + 2048))[0],
               b1 = ((const float4*)(xr + 2048))[1];
        uint4 oe = {pack2bf(a0.x + b0.x, a0.y + b0.y),
                    pack2bf(a0.z + b0.z, a0.w + b0.w),
                    pack2bf(a1.x + b1.x, a1.y + b1.y),
                    pack2bf(a1.z + b1.z, a1.w + b1.w)};
        *(uint4*)(xe + i) = oe;
        uint4 oo = {pack2bf(a0.x - b0.x, a0.y - b0.y),
                    pack2bf(a0.z - b0.z, a0.w - b0.w),
                    pack2bf(a1.x - b1.x, a1.y - b1.y),
                    pack2bf(a1.z - b1.z, a1.w - b1.w)};
        *(uint4*)(xo + i) = oo;
    } else if (b < 3072) {
        unsigned i = ((b - 1024) * 256u + tid) * 8u;
        int r = i >> 11, j0 = i & 2047;
        const float inv_n = 1.0f / 4096.0f;
        float v[8];
        if (r < 512) {
            if (r == 0) {
                #pragma unroll
                for (int u = 0; u < 8; ++u) v[u] = inv_n;
            } else {
                #pragma unroll
                for (int u = 0; u < 8; ++u) {
                    int t = (r * (j0 + u)) & 2047;
                    v[u] = 2.0f * inv_n * cosf((float)t * (PI2 / 2048.0f));
                }
            }
        } else if (r < 1024) {
            int m = r - 512;
            #pragma unroll
            for (int u = 0; u < 8; ++u) {
                int t = (m * (j0 + u)) & 2047;
                v[u] = -2.0f * inv_n * sinf((float)t * (PI2 / 2048.0f));
            }
        } else if (r < 1536) {
            int c = 2 * (r - 1024) + 1;
            #pragma unroll
            for (int u = 0; u < 8; ++u) {
                int t = (c * (j0 + u)) & 4095;
                v[u] = 2.0f * inv_n * cosf((float)t * (PI2 / 4096.0f));
            }
        } else {
            int m = 2 * (r - 1536) + 1;
            #pragma unroll
            for (int u = 0; u < 8; ++u) {
                int t = (m * (j0 + u)) & 4095;
                v[u] = -2.0f * inv_n * sinf((float)t * (PI2 / 4096.0f));
            }
        }
        uint4 o = {pack2bf(v[0], v[1]), pack2bf(v[2], v[3]),
                   pack2bf(v[4], v[5]), pack2bf(v[6], v[7])};
        *(uint4*)(B1f + i) = o;
    } else if (b < 3584) {
        // LDS-tiled V transpose + S-mul + k-fold. 256 blocks per matrix:
        // tile-pair (tkk, tkk+16) x c-tile tc; 64x64 f32 tiles.
        const int bb  = b - 3072;
        const int m   = bb >> 8;           // 0 = Vr, 1 = Vi
        const int tt  = bb & 255;
        const int tkk = tt >> 4;           // 0..15 -> k rows tkk*64, +1024
        const int tc  = tt & 15;
        const float* srcA = (m ? Vi : Vr) + (size_t)(tkk * 64) * 1024 + tc * 64;
        const float* srcB = srcA + (size_t)1024 * 1024;   // k + 1024

        #pragma unroll
        for (int pass = 0; pass < 4; ++pass) {
            int r  = pass * 16 + (tid >> 4);        // 0..63
            int cq = (tid & 15) * 4;                // 0..60
            *(float4*)&tlds0[r][cq] = *(const float4*)(srcA + (size_t)r * 1024 + cq);
            *(float4*)&tlds1[r][cq] = *(const float4*)(srcB + (size_t)r * 1024 + cq);
        }
        if (tid < 64) {
            s_lo[tid] = S[tkk * 64 + tid];
            s_hi[tid] = S[tkk * 64 + tid + 1024];
        }
        __syncthreads();

        const int cl = tid & 63;                    // local col -> f row
        const int ch = (tid >> 6) * 16;             // k chunk
        const int c  = tc * 64 + cl;
        const int f  = ((c & 1) << 10) + (m << 9) + (c >> 1);
        float ve[16], vo[16];
        #pragma unroll
        for (int j = 0; j < 16; ++j) {
            float a  = tlds0[ch + j][cl] * s_lo[ch + j];
            float bb2 = tlds1[ch + j][cl] * s_hi[ch + j];
            ve[j] = a + bb2;
            vo[j] = a - bb2;
        }
        uint4* de = (uint4*)(VSe + (size_t)f * 1024 + tkk * 64 + ch);
        de[0] = (uint4){pack2bf(ve[0],  ve[1]),  pack2bf(ve[2],  ve[3]),
                        pack2bf(ve[4],  ve[5]),  pack2bf(ve[6],  ve[7])};
        de[1] = (uint4){pack2bf(ve[8],  ve[9]),  pack2bf(ve[10], ve[11]),
                        pack2bf(ve[12], ve[13]), pack2bf(ve[14], ve[15])};
        uint4* dox = (uint4*)(VSo + (size_t)f * 1024 + tkk * 64 + ch);
        dox[0] = (uint4){pack2bf(vo[0],  vo[1]),  pack2bf(vo[2],  vo[3]),
                         pack2bf(vo[4],  vo[5]),  pack2bf(vo[6],  vo[7])};
        dox[1] = (uint4){pack2bf(vo[8],  vo[9]),  pack2bf(vo[10], vo[11]),
                         pack2bf(vo[12], vo[13]), pack2bf(vo[14], vo[15])};
    } else if (b < 4096) {
        // B2' (1024x1024), parity-grouped rows, no S
        unsigned i = ((b - 3584) * 256u + tid) * 8u;
        int p = i >> 10, k0 = i & 1023;
        int grp = p >> 8, pp = p & 255;
        const float inv_n = 1.0f / 2048.0f;
        float v[8];
        if (grp == 0) {
            if (p == 0) {
                #pragma unroll
                for (int u = 0; u < 8; ++u) v[u] = inv_n;
            } else {
                #pragma unroll
                for (int u = 0; u < 8; ++u) {
                    int t = (pp * (k0 + u)) & 1023;      // cos F=2pp, 1024-per
                    v[u] = 2.0f * inv_n * cosf((float)t * (PI2 / 1024.0f));
                }
            }
        } else if (grp == 1) {
            #pragma unroll
            for (int u = 0; u < 8; ++u) {
                int t = (pp * (k0 + u)) & 1023;          // sin F=2pp
                v[u] = -2.0f * inv_n * sinf((float)t * (PI2 / 1024.0f));
            }
        } else if (grp == 2) {
            int q = 2 * pp + 1;
            #pragma unroll
            for (int u = 0; u < 8; ++u) {
                int t = (q * (k0 + u)) & 2047;           // cos F=2pp+1
                v[u] = 2.0f * inv_n * cosf((float)t * (PI2 / 2048.0f));
            }
        } else {
            int q = 2 * pp + 1;
            #pragma unroll
            for (int u = 0; u < 8; ++u) {
                int t = (q * (k0 + u)) & 2047;           // sin F=2pp+1
                v[u] = -2.0f * inv_n * sinf((float)t * (PI2 / 2048.0f));
            }
        }
        uint4 o = {pack2bf(v[0], v[1]), pack2bf(v[2], v[3]),
                   pack2bf(v[4], v[5]), pack2bf(v[6], v[7])};
        *(uint4*)(B2 + i) = o;
    } else {
        // Ucat (4096x1024), columns permuted to B2' row order.
        unsigned i = ((b - 4096) * 256u + tid) * 8u;
        int o_ = i >> 10, c = i & 1023;
        int grp = c >> 8, cc = c & 255;
        int par = grp >> 1;
        const float2* s2 = (const float2*)(((grp & 1) ? Ui : Ur)
                                           + (size_t)o_ * 512 + 2 * cc);
        float v[8];
        #pragma unroll
        for (int j = 0; j < 8; ++j) {
            float2 q = s2[j];
            v[j] = par ? q.y : q.x;
        }
        uint4 o = {pack2bf(v[0], v[1]), pack2bf(v[2], v[3]),
                   pack2bf(v[4], v[5]), pack2bf(v[6], v[7])};
        *(uint4*)(Ucat + i) = o;
    }
}

// ---------------------------------------------------------------------------
// 128x128 MFMA tile core, BK=64, XOR-swizzled LDS, double-buffered
// (round-5 proven): next K-tile's global_load_lds issues BEFORE the compute
// phase; one __syncthreads() per K-step. LDS 64 KB/block -> 2 blocks/CU.
// ---------------------------------------------------------------------------
__device__ __forceinline__ void tile_core(
    const short* __restrict__ A, int lda,
    const short* __restrict__ B, int ldb, int K,
    short* As, short* Bs, int bm, int bn, f32x4 (&acc)[4][4])
{
    const int tid  = threadIdx.x;
    const int wave = tid >> 6;
    const int lane = tid & 63;
    const int wm   = (wave >> 1) << 6;
    const int wn   = (wave & 1) << 6;
    const int l16  = lane & 15;
    const int quad = lane >> 4;
    const int rk   = l16 & 7;

    int aoff[4], boff[4], loff[4];
    #pragma unroll
    for (int p = 0; p < 4; ++p) {
        int L   = p * 256 + wave * 64 + lane;
        int row = L >> 3;
        int swz = (L & 7) ^ (row & 7);
        aoff[p] = (bm + row) * lda + swz * 8;
        boff[p] = (bn + row) * ldb + swz * 8;
        loff[p] = L * 8;
    }

    // prologue: stage K-tile 0 into buffer 0
    #pragma unroll
    for (int p = 0; p < 4; ++p) g2l16(A + aoff[p], As + loff[p]);
    #pragma unroll
    for (int p = 0; p < 4; ++p) g2l16(B + boff[p], Bs + loff[p]);
    __syncthreads();

    int cur = 0;
    for (int k0 = 0; k0 < K; k0 += 64) {
        const int nxt = cur ^ 1;
        if (k0 + 64 < K) {
            #pragma unroll
            for (int p = 0; p < 4; ++p)
                g2l16(A + aoff[p] + k0 + 64, As + nxt * 8192 + loff[p]);
            #pragma unroll
            for (int p = 0; p < 4; ++p)
                g2l16(B + boff[p] + k0 + 64, Bs + nxt * 8192 + loff[p]);
        }

        const short* Asc = As + cur * 8192;
        const short* Bsc = Bs + cur * 8192;
        #pragma unroll
        for (int h = 0; h < 2; ++h) {
            const int cs8 = ((((h << 2) | quad) ^ rk) << 3);
            bf16x8 b[4];
            #pragma unroll
            for (int nt = 0; nt < 4; ++nt)
                b[nt] = *(const bf16x8*)(Bsc + (wn + nt * 16 + l16) * 64 + cs8);
            #pragma unroll
            for (int mt = 0; mt < 4; ++mt) {
                bf16x8 a = *(const bf16x8*)(Asc + (wm + mt * 16 + l16) * 64 + cs8);
                #pragma unroll
                for (int nt = 0; nt < 4; ++nt)
                    acc[mt][nt] = __builtin_amdgcn_mfma_f32_16x16x32_bf16(
                        a, b[nt], acc[mt][nt], 0, 0, 0);
            }
        }
        __syncthreads();
        cur = nxt;
    }
}

__device__ __forceinline__ void store_tile_bf16(
    f32x4 (&acc)[4][4], short* __restrict__ C, int ldc, int bm, int bn)
{
    const int tid  = threadIdx.x;
    const int wave = tid >> 6;
    const int lane = tid & 63;
    const int wm   = (wave >> 1) << 6;
    const int wn   = (wave & 1) << 6;
    const int l16  = lane & 15;
    const int quad = lane >> 4;
    #pragma unroll
    for (int nt = 0; nt < 4; ++nt) {
        int col = bn + wn + nt * 16 + l16;
        #pragma unroll
        for (int mt = 0; mt < 4; ++mt) {
            int rowb = bm + wm + mt * 16 + quad * 4;
            #pragma unroll
            for (int r = 0; r < 4; ++r)
                C[(size_t)(rowb + r) * ldc + col] = f2bf(acc[mt][nt][r]);
        }
    }
}

// Fragment-layout store: 8 coalesced uint4 per thread.
__device__ __forceinline__ void store_frag(
    f32x4 (&acc)[4][4], short* __restrict__ planeTile)
{
    uint4* p = (uint4*)planeTile;
    const int tid = threadIdx.x;
    #pragma unroll
    for (int c = 0; c < 8; ++c) {
        int nt = c >> 1, mt0 = (c & 1) * 2;
        uint4 o = {pack2bf(acc[mt0][nt][0],     acc[mt0][nt][1]),
                   pack2bf(acc[mt0][nt][2],     acc[mt0][nt][3]),
                   pack2bf(acc[mt0 + 1][nt][0], acc[mt0 + 1][nt][1]),
                   pack2bf(acc[mt0 + 1][nt][2], acc[mt0 + 1][nt][3])};
        p[c * 256 + tid] = o;
    }
}

// Reduce one fragment chunk (tile, c) across SK planes -> row-major output.
template <bool OUT_F32>
__device__ __forceinline__ void reduce_unit(
    const short* __restrict__ P, size_t planeU4, int SK,
    int tile, int c, int tilesX, void* __restrict__ Out, int ldc,
    const float* __restrict__ bias)
{
    const int bm = (tile / tilesX) << 7;
    const int bn = (tile % tilesX) << 7;
    const int tid  = threadIdx.x;
    const int wave = tid >> 6;
    const int lane = tid & 63;
    const int wm   = (wave >> 1) << 6;
    const int wn   = (wave & 1) << 6;
    const int l16  = lane & 15;
    const int quad = lane >> 4;
    const int nt   = c >> 1, mt0 = (c & 1) * 2;

    const uint4* P4 = (const uint4*)P;
    const size_t base = (size_t)tile * 2048 + (size_t)c * 256 + tid;
    float f[8] = {0, 0, 0, 0, 0, 0, 0, 0};
    for (int z = 0; z < SK; ++z) {
        uint4 v = P4[(size_t)z * planeU4 + base];
        f[0] += bflo(v.x); f[1] += bfhi(v.x);
        f[2] += bflo(v.y); f[3] += bfhi(v.y);
        f[4] += bflo(v.z); f[5] += bfhi(v.z);
        f[6] += bflo(v.w); f[7] += bfhi(v.w);
    }
    const int col = bn + wn + nt * 16 + l16;
    float bv = 0.f;
    if (OUT_F32) bv = bias[col];
    #pragma unroll
    for (int j = 0; j < 8; ++j) {
        int mt  = mt0 + (j >> 2);
        int row = bm + wm + mt * 16 + quad * 4 + (j & 3);
        if (OUT_F32)
            ((float*)Out)[(size_t)row * ldc + col] = f[j] + bv;
        else
            ((short*)Out)[(size_t)row * ldc + col] = f2bf(f[j]);
    }
}

// ---------------------------------------------------------------------------
// Merged dispatch: blocks [0,512)   = folded stage-1 split-K GEMM (SK=4,
//                                     Kpart=512) -> s1 partial planes;
//                  blocks [512,1024)= W2 = B2' @ VS?^T (1024x2048, K=1024
//                                     after k-fold; SK=4, Kpart=256).
//                  Row group selects VSe (even freq, bm<512) or VSo.
// ---------------------------------------------------------------------------
__global__ __launch_bounds__(256, 2) void gemm_s1w2(
    const short* __restrict__ xe, const short* __restrict__ xo,
    const short* __restrict__ B1f,
    const short* __restrict__ B2,
    const short* __restrict__ VSe, const short* __restrict__ VSo,
    short* __restrict__ P, short* __restrict__ PW)
{
    __shared__ __align__(16) short As[2 * 128 * 64];
    __shared__ __align__(16) short Bs[2 * 128 * 64];

    f32x4 acc[4][4];
    #pragma unroll
    for (int i = 0; i < 4; ++i)
        #pragma unroll
        for (int j = 0; j < 4; ++j)
            acc[i][j] = (f32x4){0.f, 0.f, 0.f, 0.f};

    const int raw = (int)blockIdx.x;
    if (raw < 512) {
        const int u    = xcd_swizzle(raw, 512);
        const int z    = u >> 7;          // SK = 4
        const int tile = u & 127;         // 8 x 16 tiles
        const int tx   = tile & 15, ty = tile >> 4;
        const bool odd = (tx & 8) != 0;
        const short* A = (odd ? xo : xe) + (size_t)z * 512;
        const short* B = B1f + (odd ? (size_t)1024 * 2048 : 0) + (size_t)z * 512;
        const int bm   = ty << 7;
        const int bn   = (tx & 7) << 7;

        tile_core(A, 2048, B, 2048, 512, As, Bs, bm, bn, acc);
        store_frag(acc, P + (size_t)z * 2097152 + (size_t)tile * 16384);
    } else {
        const int u    = xcd_swizzle(raw - 512, 512);
        const int z    = u >> 7;          // SK = 4, Kpart = 256
        const int tile = u & 127;         // 8(p) x 16(f) tiles
        const int bm   = (tile >> 4) << 7;
        const int bn   = (tile & 15) << 7;
        const short* Bv = (bm < 512) ? VSe : VSo;   // freq-parity group

        tile_core(B2 + (size_t)z * 256, 1024, Bv + (size_t)z * 256, 1024,
                  256, As, Bs, bm, bn, acc);
        store_frag(acc, PW + (size_t)z * 2097152 + (size_t)tile * 16384);
    }
}

// Merged reduce: blocks [0,1024) -> Xp from P; [1024,2048) -> W2 from PW.
__global__ __launch_bounds__(256) void reduce_s1w2(
    const short* __restrict__ P, const short* __restrict__ PW,
    short* __restrict__ Xp, short* __restrict__ W2)
{
    const int b   = (int)blockIdx.x;
    const int sub = b & 1023;
    if (b < 1024)
        reduce_unit<false>(P,  (size_t)2097152 >> 3, 4, sub >> 3, sub & 7,
                           16, Xp, 2048, nullptr);
    else
        reduce_unit<false>(PW, (size_t)2097152 >> 3, 4, sub >> 3, sub & 7,
                           16, W2, 2048, nullptr);
}

// ---------------------------------------------------------------------------
// Generic split-K GEMM into fragment-layout bf16 partial planes.
// ---------------------------------------------------------------------------
__global__ __launch_bounds__(256, 2) void gemm_sk_frag(
    const short* __restrict__ A, int lda,
    const short* __restrict__ B, int ldb,
    short* __restrict__ P, size_t planeShorts, int Kpart,
    int tileShift, int tilesXShift)
{
    __shared__ __align__(16) short As[2 * 128 * 64];
    __shared__ __align__(16) short Bs[2 * 128 * 64];

    f32x4 acc[4][4];
    #pragma unroll
    for (int i = 0; i < 4; ++i)
        #pragma unroll
        for (int j = 0; j < 4; ++j)
            acc[i][j] = (f32x4){0.f, 0.f, 0.f, 0.f};

    const int u    = xcd_swizzle((int)blockIdx.x, (int)gridDim.x);
    const int z    = u >> tileShift;
    const int tile = u & ((1 << tileShift) - 1);
    const int bm   = (tile >> tilesXShift) << 7;
    const int bn   = (tile & ((1 << tilesXShift) - 1)) << 7;

    tile_core(A + (size_t)z * Kpart, lda, B + (size_t)z * Kpart, ldb, Kpart,
              As, Bs, bm, bn, acc);
    store_frag(acc, P + (size_t)z * planeShorts + (size_t)tile * 16384);
}

template <bool OUT_F32>
__global__ __launch_bounds__(256) void reduce_frag(
    const short* __restrict__ P, size_t planeShorts, int SK,
    int tilesX, void* __restrict__ Out, int ldc,
    const float* __restrict__ bias)
{
    reduce_unit<OUT_F32>(P, planeShorts >> 3, SK,
                         (int)(blockIdx.x >> 3), (int)(blockIdx.x & 7),
                         tilesX, Out, ldc, bias);
}

// ---------------------------------------------------------------------------
// Direct GEMM for the small-ws fallback path
// ---------------------------------------------------------------------------
template <bool OUT_F32>
__global__ __launch_bounds__(256, 2) void gemm_direct(
    const short* __restrict__ A, int lda,
    const short* __restrict__ B, int ldb,
    void* __restrict__ Cv, int ldc,
    const float* __restrict__ bias, int K)
{
    __shared__ __align__(16) short As[2 * 128 * 64];
    __shared__ __align__(16) short Bs[2 * 128 * 64];

    f32x4 acc[4][4];
    #pragma unroll
    for (int i = 0; i < 4; ++i)
        #pragma unroll
        for (int j = 0; j < 4; ++j)
            acc[i][j] = (f32x4){0.f, 0.f, 0.f, 0.f};

    const int bm = blockIdx.y << 7;
    const int bn = blockIdx.x << 7;
    tile_core(A, lda, B, ldb, K, As, Bs, bm, bn, acc);

    const int tid  = threadIdx.x;
    const int wave = tid >> 6;
    const int lane = tid & 63;
    const int wm   = (wave >> 1) << 6;
    const int wn   = (wave & 1) << 6;
    const int l16  = lane & 15;
    const int quad = lane >> 4;

    if (OUT_F32) {
        float* C = (float*)Cv;
        #pragma unroll
        for (int nt = 0; nt < 4; ++nt) {
            int col = bn + wn + nt * 16 + l16;
            float bv = bias ? bias[col] : 0.f;
            #pragma unroll
            for (int mt = 0; mt < 4; ++mt) {
                int rowb = bm + wm + mt * 16 + quad * 4;
                #pragma unroll
                for (int r = 0; r < 4; ++r)
                    C[(size_t)(rowb + r) * ldc + col] = acc[mt][nt][r] + bv;
            }
        }
    } else {
        store_tile_bf16(acc, (short*)Cv, ldc, bm, bn);
    }
}

// Fallback stage-1 (full K), 128 blocks.
__global__ __launch_bounds__(256, 2) void gemm_s1f_dir(
    const short* __restrict__ xe, const short* __restrict__ xo,
    const short* __restrict__ B1f, short* __restrict__ Xp)
{
    __shared__ __align__(16) short As[2 * 128 * 64];
    __shared__ __align__(16) short Bs[2 * 128 * 64];

    f32x4 acc[4][4];
    #pragma unroll
    for (int i = 0; i < 4; ++i)
        #pragma unroll
        for (int j = 0; j < 4; ++j)
            acc[i][j] = (f32x4){0.f, 0.f, 0.f, 0.f};

    const int u    = (int)blockIdx.x;
    const int tx   = u & 15, ty = u >> 4;
    const bool odd = (tx & 8) != 0;
    const short* A = odd ? xo : xe;
    const short* B = B1f + (odd ? (size_t)1024 * 2048 : 0);
    const int bm   = ty << 7;
    const int bn   = (tx & 7) << 7;

    tile_core(A, 2048, B, 2048, 2048, As, Bs, bm, bn, acc);
    store_tile_bf16(acc, Xp, 2048, bm, bn + (odd ? 1024 : 0));
}

extern "C" void kernel_launch(void* const* d_in, const int* in_sizes, int n_in,
                              void* d_out, int out_size, void* d_ws, size_t ws_size,
                              hipStream_t stream) {
    const float* x    = (const float*)d_in[0];
    const float* Ur   = (const float*)d_in[1];
    const float* Ui   = (const float*)d_in[2];
    const float* S    = (const float*)d_in[3];
    const float* Vr   = (const float*)d_in[4];
    const float* Vi   = (const float*)d_in[5];
    const float* bias = (const float*)d_in[6];
    float* out = (float*)d_out;

    short* ws    = (short*)d_ws;
    short* xe    = ws;                                  // 1024*2048
    short* xo    = xe    + (size_t)1024 * 2048;         // 1024*2048
    short* B1f   = xo    + (size_t)1024 * 2048;         // 2048*2048
    short* VSe   = B1f   + (size_t)2048 * 2048;         // 2048*1024
    short* VSo   = VSe   + (size_t)2048 * 1024;         // 2048*1024
    short* B2    = VSo   + (size_t)2048 * 1024;         // 1024*1024
    short* Ucat  = B2    + (size_t)1024 * 1024;         // 4096*1024
    short* Xp    = Ucat  + (size_t)4096 * 1024;         // 1024*2048
    short* W2    = Xp    + (size_t)1024 * 2048;         // 1024*2048
    short* Gm    = W2    + (size_t)1024 * 2048;         // 1024*1024
    short* Pp    = Gm    + (size_t)1024 * 1024;         // partials 8.39M shorts
    short* PW    = Pp    + (size_t)8388608;             // W2 partials 8.39M

    const size_t need = (size_t)((char*)(PW + (size_t)8388608) - (char*)d_ws);

    aux_all8<<<dim3(6144), 256, 0, stream>>>(
        x, Ur, Ui, S, Vr, Vi, xe, xo, B1f, VSe, VSo, B2, Ucat);

    if (ws_size >= need) {
        // [s1 || W2] merged (1024 blocks; s1 SK=4 Kpart=512, W2 SK=4 Kpart=256)
        gemm_s1w2<<<dim3(1024), 256, 0, stream>>>(
            xe, xo, B1f, B2, VSe, VSo, Pp, PW);
        reduce_s1w2<<<dim3(2048), 256, 0, stream>>>(Pp, PW, Xp, W2);

        // G = Xp @ W2^T (1024x1024, K=2048; SK=8, Kpart=256, 512 blocks)
        gemm_sk_frag<<<dim3(512), 256, 0, stream>>>(
            Xp, 2048, W2, 2048, Pp, (size_t)1048576, 256, 6, 3);
        reduce_frag<false><<<dim3(512), 256, 0, stream>>>(
            Pp, (size_t)1048576, 8, 8, Gm, 1024, nullptr);

        // out = G @ Ucat^T + bias (1024x4096, K=1024; SK=2, Kpart=512)
        gemm_sk_frag<<<dim3(512), 256, 0, stream>>>(
            Gm, 1024, Ucat, 1024, Pp, (size_t)4194304, 512, 8, 5);
        reduce_frag<true><<<dim3(2048), 256, 0, stream>>>(
            Pp, (size_t)4194304, 2, 32, out, 4096, bias);
    } else {
        gemm_s1f_dir<<<dim3(128), 256, 0, stream>>>(xe, xo, B1f, Xp);
        // W2 rows [0,512) even-freq group vs VSe; rows [512,1024) vs VSo
        gemm_direct<false><<<dim3(16, 4), 256, 0, stream>>>(
            B2, 1024, VSe, 1024, W2, 2048, nullptr, 1024);
        gemm_direct<false><<<dim3(16, 4), 256, 0, stream>>>(
            B2 + (size_t)512 * 1024, 1024, VSo, 1024,
            W2 + (size_t)512 * 2048, 2048, nullptr, 1024);
        gemm_direct<false><<<dim3(8, 8), 256, 0, stream>>>(
            Xp, 2048, W2, 2048, Gm, 1024, nullptr, 2048);
        gemm_direct<true><<<dim3(32, 8), 256, 0, stream>>>(
            Gm, 1024, Ucat, 1024, out, 4096, bias, 1024);
    }
}

// Round 11
// 164.366 us; speedup vs baseline: 1.3651x; 1.0079x over previous
//
#include <hip/hip_runtime.h>
#include <math.h>
#include <stdint.h>

#define PI2 6.28318530717958647692f

typedef __bf16 bf16x8 __attribute__((ext_vector_type(8)));
typedef float f32x4 __attribute__((ext_vector_type(4)));

typedef __attribute__((address_space(1))) const void gvoid_t;
typedef __attribute__((address_space(3))) void lvoid_t;

__device__ __forceinline__ void g2l16(const void* g, void* l) {
    __builtin_amdgcn_global_load_lds(
        reinterpret_cast<gvoid_t*>(reinterpret_cast<uintptr_t>(g)),
        reinterpret_cast<lvoid_t*>(reinterpret_cast<uintptr_t>(l)),
        16, 0, 0);
}

__device__ __forceinline__ short f2bf(float f) {
    unsigned u = __float_as_uint(f);
    u += 0x7FFFu + ((u >> 16) & 1u);          // round-to-nearest-even
    return (short)(u >> 16);
}

__device__ __forceinline__ unsigned pack2bf(float a, float b) {
    return (unsigned)(unsigned short)f2bf(a) |
           ((unsigned)(unsigned short)f2bf(b) << 16);
}

__device__ __forceinline__ float bflo(unsigned v) { return __uint_as_float(v << 16); }
__device__ __forceinline__ float bfhi(unsigned v) { return __uint_as_float(v & 0xFFFF0000u); }

// XCD-locality swizzle (G must be a multiple of 8 -> bijective).
__device__ __forceinline__ int xcd_swizzle(int blk, int G) {
    return (blk & 7) * (G >> 3) + (blk >> 3);
}

// ---------------------------------------------------------------------------
// Fused aux kernel, block-range dispatch, 6144 blocks:
//   [0,   1024): xe/xo radix-2 fold of x (1024x2048 each, bf16)
//   [1024,3072): B1f folded DFT basis (2048x2048)
//   [3072,3584): VSe/VSo via LDS transpose + S-multiply + k-radix-2 fold
//   [3584,4096): B2' (1024x1024), frequency-parity row groups
//   [4096,6144): Ucat (4096x1024) permuted to match B2' row order
// ---------------------------------------------------------------------------
__global__ __launch_bounds__(256) void aux_all8(
    const float* __restrict__ x,
    const float* __restrict__ Ur, const float* __restrict__ Ui,
    const float* __restrict__ S,
    const float* __restrict__ Vr, const float* __restrict__ Vi,
    short* __restrict__ xe, short* __restrict__ xo,
    short* __restrict__ B1f, short* __restrict__ VSe, short* __restrict__ VSo,
    short* __restrict__ B2, short* __restrict__ Ucat)
{
    __shared__ float tlds0[64][68];
    __shared__ float tlds1[64][68];
    __shared__ float s_lo[64], s_hi[64];
    const int b   = (int)blockIdx.x;
    const int tid = threadIdx.x;

    if (b < 1024) {
        // radix-2 fold: xe = x[:, :2048] + x[:, 2048:], xo = difference
        unsigned i = (b * 256u + tid) * 8u;
        int r = i >> 11, j0 = i & 2047;
        const float* xr = x + (size_t)r * 4096 + j0;
        float4 a0 = ((const float4*)xr)[0], a1 = ((const float4*)xr)[1];
        float4 b0 = ((const float4*)(xr + 2048))[0],
               b1 = ((const float4*)(xr + 2048))[1];
        uint4 oe = {pack2bf(a0.x + b0.x, a0.y + b0.y),
                    pack2bf(a0.z + b0.z, a0.w + b0.w),
                    pack2bf(a1.x + b1.x, a1.y + b1.y),
                    pack2bf(a1.z + b1.z, a1.w + b1.w)};
        *(uint4*)(xe + i) = oe;
        uint4 oo = {pack2bf(a0.x - b0.x, a0.y - b0.y),
                    pack2bf(a0.z - b0.z, a0.w - b0.w),
                    pack2bf(a1.x - b1.x, a1.y - b1.y),
                    pack2bf(a1.z - b1.z, a1.w - b1.w)};
        *(uint4*)(xo + i) = oo;
    } else if (b < 3072) {
        unsigned i = ((b - 1024) * 256u + tid) * 8u;
        int r = i >> 11, j0 = i & 2047;
        const float inv_n = 1.0f / 4096.0f;
        float v[8];
        if (r < 512) {
            if (r == 0) {
                #pragma unroll
                for (int u = 0; u < 8; ++u) v[u] = inv_n;
            } else {
                #pragma unroll
                for (int u = 0; u < 8; ++u) {
                    int t = (r * (j0 + u)) & 2047;
                    v[u] = 2.0f * inv_n * cosf((float)t * (PI2 / 2048.0f));
                }
            }
        } else if (r < 1024) {
            int m = r - 512;
            #pragma unroll
            for (int u = 0; u < 8; ++u) {
                int t = (m * (j0 + u)) & 2047;
                v[u] = -2.0f * inv_n * sinf((float)t * (PI2 / 2048.0f));
            }
        } else if (r < 1536) {
            int c = 2 * (r - 1024) + 1;
            #pragma unroll
            for (int u = 0; u < 8; ++u) {
                int t = (c * (j0 + u)) & 4095;
                v[u] = 2.0f * inv_n * cosf((float)t * (PI2 / 4096.0f));
            }
        } else {
            int m = 2 * (r - 1536) + 1;
            #pragma unroll
            for (int u = 0; u < 8; ++u) {
                int t = (m * (j0 + u)) & 4095;
                v[u] = -2.0f * inv_n * sinf((float)t * (PI2 / 4096.0f));
            }
        }
        uint4 o = {pack2bf(v[0], v[1]), pack2bf(v[2], v[3]),
                   pack2bf(v[4], v[5]), pack2bf(v[6], v[7])};
        *(uint4*)(B1f + i) = o;
    } else if (b < 3584) {
        // LDS-tiled V transpose + S-mul + k-fold. 256 blocks per matrix.
        const int bb  = b - 3072;
        const int m   = bb >> 8;           // 0 = Vr, 1 = Vi
        const int tt  = bb & 255;
        const int tkk = tt >> 4;           // 0..15 -> k rows tkk*64, +1024
        const int tc  = tt & 15;
        const float* srcA = (m ? Vi : Vr) + (size_t)(tkk * 64) * 1024 + tc * 64;
        const float* srcB = srcA + (size_t)1024 * 1024;   // k + 1024

        #pragma unroll
        for (int pass = 0; pass < 4; ++pass) {
            int r  = pass * 16 + (tid >> 4);        // 0..63
            int cq = (tid & 15) * 4;                // 0..60
            *(float4*)&tlds0[r][cq] = *(const float4*)(srcA + (size_t)r * 1024 + cq);
            *(float4*)&tlds1[r][cq] = *(const float4*)(srcB + (size_t)r * 1024 + cq);
        }
        if (tid < 64) {
            s_lo[tid] = S[tkk * 64 + tid];
            s_hi[tid] = S[tkk * 64 + tid + 1024];
        }
        __syncthreads();

        const int cl = tid & 63;                    // local col -> f row
        const int ch = (tid >> 6) * 16;             // k chunk
        const int c  = tc * 64 + cl;
        const int f  = ((c & 1) << 10) + (m << 9) + (c >> 1);
        float ve[16], vo[16];
        #pragma unroll
        for (int j = 0; j < 16; ++j) {
            float a   = tlds0[ch + j][cl] * s_lo[ch + j];
            float bb2 = tlds1[ch + j][cl] * s_hi[ch + j];
            ve[j] = a + bb2;
            vo[j] = a - bb2;
        }
        uint4* de = (uint4*)(VSe + (size_t)f * 1024 + tkk * 64 + ch);
        de[0] = (uint4){pack2bf(ve[0],  ve[1]),  pack2bf(ve[2],  ve[3]),
                        pack2bf(ve[4],  ve[5]),  pack2bf(ve[6],  ve[7])};
        de[1] = (uint4){pack2bf(ve[8],  ve[9]),  pack2bf(ve[10], ve[11]),
                        pack2bf(ve[12], ve[13]), pack2bf(ve[14], ve[15])};
        uint4* dox = (uint4*)(VSo + (size_t)f * 1024 + tkk * 64 + ch);
        dox[0] = (uint4){pack2bf(vo[0],  vo[1]),  pack2bf(vo[2],  vo[3]),
                         pack2bf(vo[4],  vo[5]),  pack2bf(vo[6],  vo[7])};
        dox[1] = (uint4){pack2bf(vo[8],  vo[9]),  pack2bf(vo[10], vo[11]),
                         pack2bf(vo[12], vo[13]), pack2bf(vo[14], vo[15])};
    } else if (b < 4096) {
        // B2' (1024x1024), parity-grouped rows, no S
        unsigned i = ((b - 3584) * 256u + tid) * 8u;
        int p = i >> 10, k0 = i & 1023;
        int grp = p >> 8, pp = p & 255;
        const float inv_n = 1.0f / 2048.0f;
        float v[8];
        if (grp == 0) {
            if (p == 0) {
                #pragma unroll
                for (int u = 0; u < 8; ++u) v[u] = inv_n;
            } else {
                #pragma unroll
                for (int u = 0; u < 8; ++u) {
                    int t = (pp * (k0 + u)) & 1023;      // cos F=2pp
                    v[u] = 2.0f * inv_n * cosf((float)t * (PI2 / 1024.0f));
                }
            }
        } else if (grp == 1) {
            #pragma unroll
            for (int u = 0; u < 8; ++u) {
                int t = (pp * (k0 + u)) & 1023;          // sin F=2pp
                v[u] = -2.0f * inv_n * sinf((float)t * (PI2 / 1024.0f));
            }
        } else if (grp == 2) {
            int q = 2 * pp + 1;
            #pragma unroll
            for (int u = 0; u < 8; ++u) {
                int t = (q * (k0 + u)) & 2047;           // cos F=2pp+1
                v[u] = 2.0f * inv_n * cosf((float)t * (PI2 / 2048.0f));
            }
        } else {
            int q = 2 * pp + 1;
            #pragma unroll
            for (int u = 0; u < 8; ++u) {
                int t = (q * (k0 + u)) & 2047;           // sin F=2pp+1
                v[u] = -2.0f * inv_n * sinf((float)t * (PI2 / 2048.0f));
            }
        }
        uint4 o = {pack2bf(v[0], v[1]), pack2bf(v[2], v[3]),
                   pack2bf(v[4], v[5]), pack2bf(v[6], v[7])};
        *(uint4*)(B2 + i) = o;
    } else {
        // Ucat (4096x1024), columns permuted to B2' row order.
        unsigned i = ((b - 4096) * 256u + tid) * 8u;
        int o_ = i >> 10, c = i & 1023;
        int grp = c >> 8, cc = c & 255;
        int par = grp >> 1;
        const float2* s2 = (const float2*)(((grp & 1) ? Ui : Ur)
                                           + (size_t)o_ * 512 + 2 * cc);
        float v[8];
        #pragma unroll
        for (int j = 0; j < 8; ++j) {
            float2 q = s2[j];
            v[j] = par ? q.y : q.x;
        }
        uint4 o = {pack2bf(v[0], v[1]), pack2bf(v[2], v[3]),
                   pack2bf(v[4], v[5]), pack2bf(v[6], v[7])};
        *(uint4*)(Ucat + i) = o;
    }
}

// ---------------------------------------------------------------------------
// 128x128 MFMA tile core, BK=64, XOR-swizzled LDS, double-buffered
// (round-5 proven): next K-tile's global_load_lds issues BEFORE the compute
// phase; one __syncthreads() per K-step. LDS 64 KB/block -> 2 blocks/CU.
// ---------------------------------------------------------------------------
__device__ __forceinline__ void tile_core(
    const short* __restrict__ A, int lda,
    const short* __restrict__ B, int ldb, int K,
    short* As, short* Bs, int bm, int bn, f32x4 (&acc)[4][4])
{
    const int tid  = threadIdx.x;
    const int wave = tid >> 6;
    const int lane = tid & 63;
    const int wm   = (wave >> 1) << 6;
    const int wn   = (wave & 1) << 6;
    const int l16  = lane & 15;
    const int quad = lane >> 4;
    const int rk   = l16 & 7;

    int aoff[4], boff[4], loff[4];
    #pragma unroll
    for (int p = 0; p < 4; ++p) {
        int L   = p * 256 + wave * 64 + lane;
        int row = L >> 3;
        int swz = (L & 7) ^ (row & 7);
        aoff[p] = (bm + row) * lda + swz * 8;
        boff[p] = (bn + row) * ldb + swz * 8;
        loff[p] = L * 8;
    }

    // prologue: stage K-tile 0 into buffer 0
    #pragma unroll
    for (int p = 0; p < 4; ++p) g2l16(A + aoff[p], As + loff[p]);
    #pragma unroll
    for (int p = 0; p < 4; ++p) g2l16(B + boff[p], Bs + loff[p]);
    __syncthreads();

    int cur = 0;
    for (int k0 = 0; k0 < K; k0 += 64) {
        const int nxt = cur ^ 1;
        if (k0 + 64 < K) {
            #pragma unroll
            for (int p = 0; p < 4; ++p)
                g2l16(A + aoff[p] + k0 + 64, As + nxt * 8192 + loff[p]);
            #pragma unroll
            for (int p = 0; p < 4; ++p)
                g2l16(B + boff[p] + k0 + 64, Bs + nxt * 8192 + loff[p]);
        }

        const short* Asc = As + cur * 8192;
        const short* Bsc = Bs + cur * 8192;
        #pragma unroll
        for (int h = 0; h < 2; ++h) {
            const int cs8 = ((((h << 2) | quad) ^ rk) << 3);
            bf16x8 b[4];
            #pragma unroll
            for (int nt = 0; nt < 4; ++nt)
                b[nt] = *(const bf16x8*)(Bsc + (wn + nt * 16 + l16) * 64 + cs8);
            #pragma unroll
            for (int mt = 0; mt < 4; ++mt) {
                bf16x8 a = *(const bf16x8*)(Asc + (wm + mt * 16 + l16) * 64 + cs8);
                #pragma unroll
                for (int nt = 0; nt < 4; ++nt)
                    acc[mt][nt] = __builtin_amdgcn_mfma_f32_16x16x32_bf16(
                        a, b[nt], acc[mt][nt], 0, 0, 0);
            }
        }
        __syncthreads();
        cur = nxt;
    }
}

__device__ __forceinline__ void store_tile_bf16(
    f32x4 (&acc)[4][4], short* __restrict__ C, int ldc, int bm, int bn)
{
    const int tid  = threadIdx.x;
    const int wave = tid >> 6;
    const int lane = tid & 63;
    const int wm   = (wave >> 1) << 6;
    const int wn   = (wave & 1) << 6;
    const int l16  = lane & 15;
    const int quad = lane >> 4;
    #pragma unroll
    for (int nt = 0; nt < 4; ++nt) {
        int col = bn + wn + nt * 16 + l16;
        #pragma unroll
        for (int mt = 0; mt < 4; ++mt) {
            int rowb = bm + wm + mt * 16 + quad * 4;
            #pragma unroll
            for (int r = 0; r < 4; ++r)
                C[(size_t)(rowb + r) * ldc + col] = f2bf(acc[mt][nt][r]);
        }
    }
}

// Fragment-layout store: 8 coalesced uint4 per thread.
__device__ __forceinline__ void store_frag(
    f32x4 (&acc)[4][4], short* __restrict__ planeTile)
{
    uint4* p = (uint4*)planeTile;
    const int tid = threadIdx.x;
    #pragma unroll
    for (int c = 0; c < 8; ++c) {
        int nt = c >> 1, mt0 = (c & 1) * 2;
        uint4 o = {pack2bf(acc[mt0][nt][0],     acc[mt0][nt][1]),
                   pack2bf(acc[mt0][nt][2],     acc[mt0][nt][3]),
                   pack2bf(acc[mt0 + 1][nt][0], acc[mt0 + 1][nt][1]),
                   pack2bf(acc[mt0 + 1][nt][2], acc[mt0 + 1][nt][3])};
        p[c * 256 + tid] = o;
    }
}

// Reduce one fragment chunk (tile, c) across SK planes -> row-major output.
template <bool OUT_F32>
__device__ __forceinline__ void reduce_unit(
    const short* __restrict__ P, size_t planeU4, int SK,
    int tile, int c, int tilesX, void* __restrict__ Out, int ldc,
    const float* __restrict__ bias)
{
    const int bm = (tile / tilesX) << 7;
    const int bn = (tile % tilesX) << 7;
    const int tid  = threadIdx.x;
    const int wave = tid >> 6;
    const int lane = tid & 63;
    const int wm   = (wave >> 1) << 6;
    const int wn   = (wave & 1) << 6;
    const int l16  = lane & 15;
    const int quad = lane >> 4;
    const int nt   = c >> 1, mt0 = (c & 1) * 2;

    const uint4* P4 = (const uint4*)P;
    const size_t base = (size_t)tile * 2048 + (size_t)c * 256 + tid;
    float f[8] = {0, 0, 0, 0, 0, 0, 0, 0};
    for (int z = 0; z < SK; ++z) {
        uint4 v = P4[(size_t)z * planeU4 + base];
        f[0] += bflo(v.x); f[1] += bfhi(v.x);
        f[2] += bflo(v.y); f[3] += bfhi(v.y);
        f[4] += bflo(v.z); f[5] += bfhi(v.z);
        f[6] += bflo(v.w); f[7] += bfhi(v.w);
    }
    const int col = bn + wn + nt * 16 + l16;
    float bv = 0.f;
    if (OUT_F32) bv = bias[col];
    #pragma unroll
    for (int j = 0; j < 8; ++j) {
        int mt  = mt0 + (j >> 2);
        int row = bm + wm + mt * 16 + quad * 4 + (j & 3);
        if (OUT_F32)
            ((float*)Out)[(size_t)row * ldc + col] = f[j] + bv;
        else
            ((short*)Out)[(size_t)row * ldc + col] = f2bf(f[j]);
    }
}

// ---------------------------------------------------------------------------
// Merged dispatch: blocks [0,512)   = folded stage-1 split-K GEMM (SK=4,
//                                     Kpart=512) -> s1 partial planes;
//                  blocks [512,1024)= W2 = B2' @ VS?^T (K=1024 after k-fold;
//                                     SK=4, Kpart=256).
// ---------------------------------------------------------------------------
__global__ __launch_bounds__(256, 2) void gemm_s1w2(
    const short* __restrict__ xe, const short* __restrict__ xo,
    const short* __restrict__ B1f,
    const short* __restrict__ B2,
    const short* __restrict__ VSe, const short* __restrict__ VSo,
    short* __restrict__ P, short* __restrict__ PW)
{
    __shared__ __align__(16) short As[2 * 128 * 64];
    __shared__ __align__(16) short Bs[2 * 128 * 64];

    f32x4 acc[4][4];
    #pragma unroll
    for (int i = 0; i < 4; ++i)
        #pragma unroll
        for (int j = 0; j < 4; ++j)
            acc[i][j] = (f32x4){0.f, 0.f, 0.f, 0.f};

    const int raw = (int)blockIdx.x;
    if (raw < 512) {
        const int u    = xcd_swizzle(raw, 512);
        const int z    = u >> 7;          // SK = 4
        const int tile = u & 127;         // 8 x 16 tiles
        const int tx   = tile & 15, ty = tile >> 4;
        const bool odd = (tx & 8) != 0;
        const short* A = (odd ? xo : xe) + (size_t)z * 512;
        const short* B = B1f + (odd ? (size_t)1024 * 2048 : 0) + (size_t)z * 512;
        const int bm   = ty << 7;
        const int bn   = (tx & 7) << 7;

        tile_core(A, 2048, B, 2048, 512, As, Bs, bm, bn, acc);
        store_frag(acc, P + (size_t)z * 2097152 + (size_t)tile * 16384);
    } else {
        const int u    = xcd_swizzle(raw - 512, 512);
        const int z    = u >> 7;          // SK = 4, Kpart = 256
        const int tile = u & 127;         // 8(p) x 16(f) tiles
        const int bm   = (tile >> 4) << 7;
        const int bn   = (tile & 15) << 7;
        const short* Bv = (bm < 512) ? VSe : VSo;   // freq-parity group

        tile_core(B2 + (size_t)z * 256, 1024, Bv + (size_t)z * 256, 1024,
                  256, As, Bs, bm, bn, acc);
        store_frag(acc, PW + (size_t)z * 2097152 + (size_t)tile * 16384);
    }
}

// Merged reduce: blocks [0,1024) -> Xp from P; [1024,2048) -> W2 from PW.
__global__ __launch_bounds__(256) void reduce_s1w2(
    const short* __restrict__ P, const short* __restrict__ PW,
    short* __restrict__ Xp, short* __restrict__ W2)
{
    const int b   = (int)blockIdx.x;
    const int sub = b & 1023;
    if (b < 1024)
        reduce_unit<false>(P,  (size_t)2097152 >> 3, 4, sub >> 3, sub & 7,
                           16, Xp, 2048, nullptr);
    else
        reduce_unit<false>(PW, (size_t)2097152 >> 3, 4, sub >> 3, sub & 7,
                           16, W2, 2048, nullptr);
}

// ---------------------------------------------------------------------------
// Generic split-K GEMM into fragment-layout bf16 partial planes.
// ---------------------------------------------------------------------------
__global__ __launch_bounds__(256, 2) void gemm_sk_frag(
    const short* __restrict__ A, int lda,
    const short* __restrict__ B, int ldb,
    short* __restrict__ P, size_t planeShorts, int Kpart,
    int tileShift, int tilesXShift)
{
    __shared__ __align__(16) short As[2 * 128 * 64];
    __shared__ __align__(16) short Bs[2 * 128 * 64];

    f32x4 acc[4][4];
    #pragma unroll
    for (int i = 0; i < 4; ++i)
        #pragma unroll
        for (int j = 0; j < 4; ++j)
            acc[i][j] = (f32x4){0.f, 0.f, 0.f, 0.f};

    const int u    = xcd_swizzle((int)blockIdx.x, (int)gridDim.x);
    const int z    = u >> tileShift;
    const int tile = u & ((1 << tileShift) - 1);
    const int bm   = (tile >> tilesXShift) << 7;
    const int bn   = (tile & ((1 << tilesXShift) - 1)) << 7;

    tile_core(A + (size_t)z * Kpart, lda, B + (size_t)z * Kpart, ldb, Kpart,
              As, Bs, bm, bn, acc);
    store_frag(acc, P + (size_t)z * planeShorts + (size_t)tile * 16384);
}

template <bool OUT_F32>
__global__ __launch_bounds__(256) void reduce_frag(
    const short* __restrict__ P, size_t planeShorts, int SK,
    int tilesX, void* __restrict__ Out, int ldc,
    const float* __restrict__ bias)
{
    reduce_unit<OUT_F32>(P, planeShorts >> 3, SK,
                         (int)(blockIdx.x >> 3), (int)(blockIdx.x & 7),
                         tilesX, Out, ldc, bias);
}

// ---------------------------------------------------------------------------
// Direct GEMM (full K): used for the final out stage (f32 + bias) and the
// small-ws fallback path. R6-proven kernel.
// ---------------------------------------------------------------------------
template <bool OUT_F32>
__global__ __launch_bounds__(256, 2) void gemm_direct(
    const short* __restrict__ A, int lda,
    const short* __restrict__ B, int ldb,
    void* __restrict__ Cv, int ldc,
    const float* __restrict__ bias, int K)
{
    __shared__ __align__(16) short As[2 * 128 * 64];
    __shared__ __align__(16) short Bs[2 * 128 * 64];

    f32x4 acc[4][4];
    #pragma unroll
    for (int i = 0; i < 4; ++i)
        #pragma unroll
        for (int j = 0; j < 4; ++j)
            acc[i][j] = (f32x4){0.f, 0.f, 0.f, 0.f};

    const int bm = blockIdx.y << 7;
    const int bn = blockIdx.x << 7;
    tile_core(A, lda, B, ldb, K, As, Bs, bm, bn, acc);

    const int tid  = threadIdx.x;
    const int wave = tid >> 6;
    const int lane = tid & 63;
    const int wm   = (wave >> 1) << 6;
    const int wn   = (wave & 1) << 6;
    const int l16  = lane & 15;
    const int quad = lane >> 4;

    if (OUT_F32) {
        float* C = (float*)Cv;
        #pragma unroll
        for (int nt = 0; nt < 4; ++nt) {
            int col = bn + wn + nt * 16 + l16;
            float bv = bias ? bias[col] : 0.f;
            #pragma unroll
            for (int mt = 0; mt < 4; ++mt) {
                int rowb = bm + wm + mt * 16 + quad * 4;
                #pragma unroll
                for (int r = 0; r < 4; ++r)
                    C[(size_t)(rowb + r) * ldc + col] = acc[mt][nt][r] + bv;
            }
        }
    } else {
        store_tile_bf16(acc, (short*)Cv, ldc, bm, bn);
    }
}

// Fallback stage-1 (full K), 128 blocks.
__global__ __launch_bounds__(256, 2) void gemm_s1f_dir(
    const short* __restrict__ xe, const short* __restrict__ xo,
    const short* __restrict__ B1f, short* __restrict__ Xp)
{
    __shared__ __align__(16) short As[2 * 128 * 64];
    __shared__ __align__(16) short Bs[2 * 128 * 64];

    f32x4 acc[4][4];
    #pragma unroll
    for (int i = 0; i < 4; ++i)
        #pragma unroll
        for (int j = 0; j < 4; ++j)
            acc[i][j] = (f32x4){0.f, 0.f, 0.f, 0.f};

    const int u    = (int)blockIdx.x;
    const int tx   = u & 15, ty = u >> 4;
    const bool odd = (tx & 8) != 0;
    const short* A = odd ? xo : xe;
    const short* B = B1f + (odd ? (size_t)1024 * 2048 : 0);
    const int bm   = ty << 7;
    const int bn   = (tx & 7) << 7;

    tile_core(A, 2048, B, 2048, 2048, As, Bs, bm, bn, acc);
    store_tile_bf16(acc, Xp, 2048, bm, bn + (odd ? 1024 : 0));
}

extern "C" void kernel_launch(void* const* d_in, const int* in_sizes, int n_in,
                              void* d_out, int out_size, void* d_ws, size_t ws_size,
                              hipStream_t stream) {
    const float* x    = (const float*)d_in[0];
    const float* Ur   = (const float*)d_in[1];
    const float* Ui   = (const float*)d_in[2];
    const float* S    = (const float*)d_in[3];
    const float* Vr   = (const float*)d_in[4];
    const float* Vi   = (const float*)d_in[5];
    const float* bias = (const float*)d_in[6];
    float* out = (float*)d_out;

    short* ws    = (short*)d_ws;
    short* xe    = ws;                                  // 1024*2048
    short* xo    = xe    + (size_t)1024 * 2048;         // 1024*2048
    short* B1f   = xo    + (size_t)1024 * 2048;         // 2048*2048
    short* VSe   = B1f   + (size_t)2048 * 2048;         // 2048*1024
    short* VSo   = VSe   + (size_t)2048 * 1024;         // 2048*1024
    short* B2    = VSo   + (size_t)2048 * 1024;         // 1024*1024
    short* Ucat  = B2    + (size_t)1024 * 1024;         // 4096*1024
    short* Xp    = Ucat  + (size_t)4096 * 1024;         // 1024*2048
    short* W2    = Xp    + (size_t)1024 * 2048;         // 1024*2048
    short* Gm    = W2    + (size_t)1024 * 2048;         // 1024*1024
    short* Pp    = Gm    + (size_t)1024 * 1024;         // partials 8.39M shorts
    short* PW    = Pp    + (size_t)8388608;             // W2 partials 8.39M

    const size_t need = (size_t)((char*)(PW + (size_t)8388608) - (char*)d_ws);

    aux_all8<<<dim3(6144), 256, 0, stream>>>(
        x, Ur, Ui, S, Vr, Vi, xe, xo, B1f, VSe, VSo, B2, Ucat);

    if (ws_size >= need) {
        // [s1 || W2] merged (1024 blocks; s1 SK=4 Kpart=512, W2 SK=4 Kpart=256)
        gemm_s1w2<<<dim3(1024), 256, 0, stream>>>(
            xe, xo, B1f, B2, VSe, VSo, Pp, PW);
        reduce_s1w2<<<dim3(2048), 256, 0, stream>>>(Pp, PW, Xp, W2);

        // G = Xp @ W2^T (1024x1024, K=2048; SK=8, Kpart=256, 512 blocks)
        gemm_sk_frag<<<dim3(512), 256, 0, stream>>>(
            Xp, 2048, W2, 2048, Pp, (size_t)1048576, 256, 6, 3);
        reduce_frag<false><<<dim3(512), 256, 0, stream>>>(
            Pp, (size_t)1048576, 8, 8, Gm, 1024, nullptr);

        // out = G @ Ucat^T + bias (1024x4096, K=1024) -- DIRECT, no reduce.
        // R6-proven kernel; deletes 2048-block reduce + 67 MB partial traffic.
        gemm_direct<true><<<dim3(32, 8), 256, 0, stream>>>(
            Gm, 1024, Ucat, 1024, out, 4096, bias, 1024);
    } else {
        gemm_s1f_dir<<<dim3(128), 256, 0, stream>>>(xe, xo, B1f, Xp);
        // W2 rows [0,512) even-freq group vs VSe; rows [512,1024) vs VSo
        gemm_direct<false><<<dim3(16, 4), 256, 0, stream>>>(
            B2, 1024, VSe, 1024, W2, 2048, nullptr, 1024);
        gemm_direct<false><<<dim3(16, 4), 256, 0, stream>>>(
            B2 + (size_t)512 * 1024, 1024, VSo, 1024,
            W2 + (size_t)512 * 2048, 2048, nullptr, 1024);
        gemm_direct<false><<<dim3(8, 8), 256, 0, stream>>>(
            Xp, 2048, W2, 2048, Gm, 1024, nullptr, 2048);
        gemm_direct<true><<<dim3(32, 8), 256, 0, stream>>>(
            Gm, 1024, Ucat, 1024, out, 4096, bias, 1024);
    }
}

// Round 12
// 159.830 us; speedup vs baseline: 1.4039x; 1.0284x over previous
//
#include <hip/hip_runtime.h>
#include <math.h>
#include <stdint.h>

#define PI2 6.28318530717958647692f

typedef __bf16 bf16x8 __attribute__((ext_vector_type(8)));
typedef float f32x4 __attribute__((ext_vector_type(4)));

typedef __attribute__((address_space(1))) const void gvoid_t;
typedef __attribute__((address_space(3))) void lvoid_t;

__device__ __forceinline__ void g2l16(const void* g, void* l) {
    __builtin_amdgcn_global_load_lds(
        reinterpret_cast<gvoid_t*>(reinterpret_cast<uintptr_t>(g)),
        reinterpret_cast<lvoid_t*>(reinterpret_cast<uintptr_t>(l)),
        16, 0, 0);
}

__device__ __forceinline__ short f2bf(float f) {
    unsigned u = __float_as_uint(f);
    u += 0x7FFFu + ((u >> 16) & 1u);          // round-to-nearest-even
    return (short)(u >> 16);
}

__device__ __forceinline__ unsigned pack2bf(float a, float b) {
    return (unsigned)(unsigned short)f2bf(a) |
           ((unsigned)(unsigned short)f2bf(b) << 16);
}

__device__ __forceinline__ float bflo(unsigned v) { return __uint_as_float(v << 16); }
__device__ __forceinline__ float bfhi(unsigned v) { return __uint_as_float(v & 0xFFFF0000u); }

// XCD-locality swizzle (G must be a multiple of 8 -> bijective).
__device__ __forceinline__ int xcd_swizzle(int blk, int G) {
    return (blk & 7) * (G >> 3) + (blk >> 3);
}

// ---------------------------------------------------------------------------
// Fused aux kernel, block-range dispatch, 5120 blocks:
//   [0,   512):  x double radix-2 fold: xee/xeo (1024x1024), xo (1024x2048)
//   [512, 1024): B1e (1024x1024): even-freq basis split by r-parity:
//                rows [0,256):   cos F=4a  over j<1024 (vs xee)
//                rows [256,512): -sin F=4a (vs xee)
//                rows [512,768): cos F=4a+2 (vs xeo)
//                rows [768,1024):-sin F=4a+2 (vs xeo)
//   [1024,2048): B1o (1024x2048): odd-freq basis (unchanged content)
//   [2048,2560): VSe/VSo via LDS transpose + S-mul + k-fold; NEW f-map:
//                c odd:  f = 1024 + m*512 + (c>>1)
//                c even: r=c>>1; f = (r&1)*512 + m*256 + (r>>1)
//   [2560,3072): B2' (1024x1024), frequency-parity row groups (unchanged)
//   [3072,5120): Ucat (4096x1024) permuted to B2' row order (unchanged)
// ---------------------------------------------------------------------------
__global__ __launch_bounds__(256) void aux_all8(
    const float* __restrict__ x,
    const float* __restrict__ Ur, const float* __restrict__ Ui,
    const float* __restrict__ S,
    const float* __restrict__ Vr, const float* __restrict__ Vi,
    short* __restrict__ xee, short* __restrict__ xeo, short* __restrict__ xo,
    short* __restrict__ B1e, short* __restrict__ B1o,
    short* __restrict__ VSe, short* __restrict__ VSo,
    short* __restrict__ B2, short* __restrict__ Ucat)
{
    __shared__ float tlds0[64][68];
    __shared__ float tlds1[64][68];
    __shared__ float s_lo[64], s_hi[64];
    const int b   = (int)blockIdx.x;
    const int tid = threadIdx.x;

    if (b < 512) {
        // double fold: xee=(x0+x2)+(x1+x3), xeo=(x0+x2)-(x1+x3),
        //              xo[j]=x0-x2, xo[j+1024]=x1-x3  (xq = x[:, q*1024+j])
        unsigned i = (b * 256u + tid) * 8u;       // 1M positions
        int r = i >> 10, j0 = i & 1023;
        const float* xr = x + (size_t)r * 4096 + j0;
        float4 p0 = ((const float4*)xr)[0],        p1 = ((const float4*)xr)[1];
        float4 q0 = ((const float4*)(xr + 1024))[0], q1 = ((const float4*)(xr + 1024))[1];
        float4 s0 = ((const float4*)(xr + 2048))[0], s1 = ((const float4*)(xr + 2048))[1];
        float4 t0 = ((const float4*)(xr + 3072))[0], t1 = ((const float4*)(xr + 3072))[1];
        float el[8] = {p0.x + s0.x, p0.y + s0.y, p0.z + s0.z, p0.w + s0.w,
                       p1.x + s1.x, p1.y + s1.y, p1.z + s1.z, p1.w + s1.w};
        float eh[8] = {q0.x + t0.x, q0.y + t0.y, q0.z + t0.z, q0.w + t0.w,
                       q1.x + t1.x, q1.y + t1.y, q1.z + t1.z, q1.w + t1.w};
        float ol[8] = {p0.x - s0.x, p0.y - s0.y, p0.z - s0.z, p0.w - s0.w,
                       p1.x - s1.x, p1.y - s1.y, p1.z - s1.z, p1.w - s1.w};
        float oh[8] = {q0.x - t0.x, q0.y - t0.y, q0.z - t0.z, q0.w - t0.w,
                       q1.x - t1.x, q1.y - t1.y, q1.z - t1.z, q1.w - t1.w};
        size_t base1k = (size_t)r * 1024 + j0;
        uint4 oee = {pack2bf(el[0] + eh[0], el[1] + eh[1]),
                     pack2bf(el[2] + eh[2], el[3] + eh[3]),
                     pack2bf(el[4] + eh[4], el[5] + eh[5]),
                     pack2bf(el[6] + eh[6], el[7] + eh[7])};
        *(uint4*)(xee + base1k) = oee;
        uint4 oeo = {pack2bf(el[0] - eh[0], el[1] - eh[1]),
                     pack2bf(el[2] - eh[2], el[3] - eh[3]),
                     pack2bf(el[4] - eh[4], el[5] - eh[5]),
                     pack2bf(el[6] - eh[6], el[7] - eh[7])};
        *(uint4*)(xeo + base1k) = oeo;
        size_t base2k = (size_t)r * 2048 + j0;
        uint4 olo = {pack2bf(ol[0], ol[1]), pack2bf(ol[2], ol[3]),
                     pack2bf(ol[4], ol[5]), pack2bf(ol[6], ol[7])};
        *(uint4*)(xo + base2k) = olo;
        uint4 ohi = {pack2bf(oh[0], oh[1]), pack2bf(oh[2], oh[3]),
                     pack2bf(oh[4], oh[5]), pack2bf(oh[6], oh[7])};
        *(uint4*)(xo + base2k + 1024) = ohi;
    } else if (b < 1024) {
        // B1e (1024x1024)
        unsigned i = ((b - 512) * 256u + tid) * 8u;
        int p = i >> 10, j0 = i & 1023;
        const float inv_n = 1.0f / 4096.0f;
        float v[8];
        if (p < 256) {
            if (p == 0) {
                #pragma unroll
                for (int u = 0; u < 8; ++u) v[u] = inv_n;
            } else {
                #pragma unroll
                for (int u = 0; u < 8; ++u) {
                    int t = (p * (j0 + u)) & 1023;           // cos F=4a
                    v[u] = 2.0f * inv_n * cosf((float)t * (PI2 / 1024.0f));
                }
            }
        } else if (p < 512) {
            int a = p - 256;
            #pragma unroll
            for (int u = 0; u < 8; ++u) {
                int t = (a * (j0 + u)) & 1023;               // -sin F=4a
                v[u] = -2.0f * inv_n * sinf((float)t * (PI2 / 1024.0f));
            }
        } else if (p < 768) {
            int q = 2 * (p - 512) + 1;
            #pragma unroll
            for (int u = 0; u < 8; ++u) {
                int t = (q * (j0 + u)) & 2047;               // cos F=4a+2
                v[u] = 2.0f * inv_n * cosf((float)t * (PI2 / 2048.0f));
            }
        } else {
            int q = 2 * (p - 768) + 1;
            #pragma unroll
            for (int u = 0; u < 8; ++u) {
                int t = (q * (j0 + u)) & 2047;               // -sin F=4a+2
                v[u] = -2.0f * inv_n * sinf((float)t * (PI2 / 2048.0f));
            }
        }
        uint4 o = {pack2bf(v[0], v[1]), pack2bf(v[2], v[3]),
                   pack2bf(v[4], v[5]), pack2bf(v[6], v[7])};
        *(uint4*)(B1e + i) = o;
    } else if (b < 2048) {
        // B1o (1024x2048): odd-freq basis over j<2048
        unsigned i = ((b - 1024) * 256u + tid) * 8u;
        int p = i >> 11, j0 = i & 2047;
        const float inv_n = 1.0f / 4096.0f;
        float v[8];
        if (p < 512) {
            int c = 2 * p + 1;
            #pragma unroll
            for (int u = 0; u < 8; ++u) {
                int t = (c * (j0 + u)) & 4095;
                v[u] = 2.0f * inv_n * cosf((float)t * (PI2 / 4096.0f));
            }
        } else {
            int m = 2 * (p - 512) + 1;
            #pragma unroll
            for (int u = 0; u < 8; ++u) {
                int t = (m * (j0 + u)) & 4095;
                v[u] = -2.0f * inv_n * sinf((float)t * (PI2 / 4096.0f));
            }
        }
        uint4 o = {pack2bf(v[0], v[1]), pack2bf(v[2], v[3]),
                   pack2bf(v[4], v[5]), pack2bf(v[6], v[7])};
        *(uint4*)(B1o + i) = o;
    } else if (b < 2560) {
        // LDS-tiled V transpose + S-mul + k-fold. 256 blocks per matrix.
        const int bb  = b - 2048;
        const int m   = bb >> 8;           // 0 = Vr, 1 = Vi
        const int tt  = bb & 255;
        const int tkk = tt >> 4;           // 0..15 -> k rows tkk*64, +1024
        const int tc  = tt & 15;
        const float* srcA = (m ? Vi : Vr) + (size_t)(tkk * 64) * 1024 + tc * 64;
        const float* srcB = srcA + (size_t)1024 * 1024;   // k + 1024

        #pragma unroll
        for (int pass = 0; pass < 4; ++pass) {
            int r  = pass * 16 + (tid >> 4);        // 0..63
            int cq = (tid & 15) * 4;                // 0..60
            *(float4*)&tlds0[r][cq] = *(const float4*)(srcA + (size_t)r * 1024 + cq);
            *(float4*)&tlds1[r][cq] = *(const float4*)(srcB + (size_t)r * 1024 + cq);
        }
        if (tid < 64) {
            s_lo[tid] = S[tkk * 64 + tid];
            s_hi[tid] = S[tkk * 64 + tid + 1024];
        }
        __syncthreads();

        const int cl = tid & 63;                    // local col -> f row
        const int ch = (tid >> 6) * 16;             // k chunk
        const int c  = tc * 64 + cl;
        int f;
        if (c & 1) {
            f = 1024 + (m << 9) + (c >> 1);
        } else {
            int r2 = c >> 1;
            f = ((r2 & 1) << 9) + (m << 8) + (r2 >> 1);
        }
        float ve[16], vo[16];
        #pragma unroll
        for (int j = 0; j < 16; ++j) {
            float a   = tlds0[ch + j][cl] * s_lo[ch + j];
            float bb2 = tlds1[ch + j][cl] * s_hi[ch + j];
            ve[j] = a + bb2;
            vo[j] = a - bb2;
        }
        uint4* de = (uint4*)(VSe + (size_t)f * 1024 + tkk * 64 + ch);
        de[0] = (uint4){pack2bf(ve[0],  ve[1]),  pack2bf(ve[2],  ve[3]),
                        pack2bf(ve[4],  ve[5]),  pack2bf(ve[6],  ve[7])};
        de[1] = (uint4){pack2bf(ve[8],  ve[9]),  pack2bf(ve[10], ve[11]),
                        pack2bf(ve[12], ve[13]), pack2bf(ve[14], ve[15])};
        uint4* dox = (uint4*)(VSo + (size_t)f * 1024 + tkk * 64 + ch);
        dox[0] = (uint4){pack2bf(vo[0],  vo[1]),  pack2bf(vo[2],  vo[3]),
                         pack2bf(vo[4],  vo[5]),  pack2bf(vo[6],  vo[7])};
        dox[1] = (uint4){pack2bf(vo[8],  vo[9]),  pack2bf(vo[10], vo[11]),
                         pack2bf(vo[12], vo[13]), pack2bf(vo[14], vo[15])};
    } else if (b < 3072) {
        // B2' (1024x1024), parity-grouped rows, no S
        unsigned i = ((b - 2560) * 256u + tid) * 8u;
        int p = i >> 10, k0 = i & 1023;
        int grp = p >> 8, pp = p & 255;
        const float inv_n = 1.0f / 2048.0f;
        float v[8];
        if (grp == 0) {
            if (p == 0) {
                #pragma unroll
                for (int u = 0; u < 8; ++u) v[u] = inv_n;
            } else {
                #pragma unroll
                for (int u = 0; u < 8; ++u) {
                    int t = (pp * (k0 + u)) & 1023;      // cos F=2pp
                    v[u] = 2.0f * inv_n * cosf((float)t * (PI2 / 1024.0f));
                }
            }
        } else if (grp == 1) {
            #pragma unroll
            for (int u = 0; u < 8; ++u) {
                int t = (pp * (k0 + u)) & 1023;          // sin F=2pp
                v[u] = -2.0f * inv_n * sinf((float)t * (PI2 / 1024.0f));
            }
        } else if (grp == 2) {
            int q = 2 * pp + 1;
            #pragma unroll
            for (int u = 0; u < 8; ++u) {
                int t = (q * (k0 + u)) & 2047;           // cos F=2pp+1
                v[u] = 2.0f * inv_n * cosf((float)t * (PI2 / 2048.0f));
            }
        } else {
            int q = 2 * pp + 1;
            #pragma unroll
            for (int u = 0; u < 8; ++u) {
                int t = (q * (k0 + u)) & 2047;           // sin F=2pp+1
                v[u] = -2.0f * inv_n * sinf((float)t * (PI2 / 2048.0f));
            }
        }
        uint4 o = {pack2bf(v[0], v[1]), pack2bf(v[2], v[3]),
                   pack2bf(v[4], v[5]), pack2bf(v[6], v[7])};
        *(uint4*)(B2 + i) = o;
    } else {
        // Ucat (4096x1024), columns permuted to B2' row order.
        unsigned i = ((b - 3072) * 256u + tid) * 8u;
        int o_ = i >> 10, c = i & 1023;
        int grp = c >> 8, cc = c & 255;
        int par = grp >> 1;
        const float2* s2 = (const float2*)(((grp & 1) ? Ui : Ur)
                                           + (size_t)o_ * 512 + 2 * cc);
        float v[8];
        #pragma unroll
        for (int j = 0; j < 8; ++j) {
            float2 q = s2[j];
            v[j] = par ? q.y : q.x;
        }
        uint4 o = {pack2bf(v[0], v[1]), pack2bf(v[2], v[3]),
                   pack2bf(v[4], v[5]), pack2bf(v[6], v[7])};
        *(uint4*)(Ucat + i) = o;
    }
}

// ---------------------------------------------------------------------------
// 128x128 MFMA tile core, BK=64, XOR-swizzled LDS, double-buffered
// (round-5 proven). LDS 64 KB/block -> 2 blocks/CU.
// ---------------------------------------------------------------------------
__device__ __forceinline__ void tile_core(
    const short* __restrict__ A, int lda,
    const short* __restrict__ B, int ldb, int K,
    short* As, short* Bs, int bm, int bn, f32x4 (&acc)[4][4])
{
    const int tid  = threadIdx.x;
    const int wave = tid >> 6;
    const int lane = tid & 63;
    const int wm   = (wave >> 1) << 6;
    const int wn   = (wave & 1) << 6;
    const int l16  = lane & 15;
    const int quad = lane >> 4;
    const int rk   = l16 & 7;

    int aoff[4], boff[4], loff[4];
    #pragma unroll
    for (int p = 0; p < 4; ++p) {
        int L   = p * 256 + wave * 64 + lane;
        int row = L >> 3;
        int swz = (L & 7) ^ (row & 7);
        aoff[p] = (bm + row) * lda + swz * 8;
        boff[p] = (bn + row) * ldb + swz * 8;
        loff[p] = L * 8;
    }

    // prologue: stage K-tile 0 into buffer 0
    #pragma unroll
    for (int p = 0; p < 4; ++p) g2l16(A + aoff[p], As + loff[p]);
    #pragma unroll
    for (int p = 0; p < 4; ++p) g2l16(B + boff[p], Bs + loff[p]);
    __syncthreads();

    int cur = 0;
    for (int k0 = 0; k0 < K; k0 += 64) {
        const int nxt = cur ^ 1;
        if (k0 + 64 < K) {
            #pragma unroll
            for (int p = 0; p < 4; ++p)
                g2l16(A + aoff[p] + k0 + 64, As + nxt * 8192 + loff[p]);
            #pragma unroll
            for (int p = 0; p < 4; ++p)
                g2l16(B + boff[p] + k0 + 64, Bs + nxt * 8192 + loff[p]);
        }

        const short* Asc = As + cur * 8192;
        const short* Bsc = Bs + cur * 8192;
        #pragma unroll
        for (int h = 0; h < 2; ++h) {
            const int cs8 = ((((h << 2) | quad) ^ rk) << 3);
            bf16x8 b[4];
            #pragma unroll
            for (int nt = 0; nt < 4; ++nt)
                b[nt] = *(const bf16x8*)(Bsc + (wn + nt * 16 + l16) * 64 + cs8);
            #pragma unroll
            for (int mt = 0; mt < 4; ++mt) {
                bf16x8 a = *(const bf16x8*)(Asc + (wm + mt * 16 + l16) * 64 + cs8);
                #pragma unroll
                for (int nt = 0; nt < 4; ++nt)
                    acc[mt][nt] = __builtin_amdgcn_mfma_f32_16x16x32_bf16(
                        a, b[nt], acc[mt][nt], 0, 0, 0);
            }
        }
        __syncthreads();
        cur = nxt;
    }
}

__device__ __forceinline__ void store_tile_bf16(
    f32x4 (&acc)[4][4], short* __restrict__ C, int ldc, int bm, int bn)
{
    const int tid  = threadIdx.x;
    const int wave = tid >> 6;
    const int lane = tid & 63;
    const int wm   = (wave >> 1) << 6;
    const int wn   = (wave & 1) << 6;
    const int l16  = lane & 15;
    const int quad = lane >> 4;
    #pragma unroll
    for (int nt = 0; nt < 4; ++nt) {
        int col = bn + wn + nt * 16 + l16;
        #pragma unroll
        for (int mt = 0; mt < 4; ++mt) {
            int rowb = bm + wm + mt * 16 + quad * 4;
            #pragma unroll
            for (int r = 0; r < 4; ++r)
                C[(size_t)(rowb + r) * ldc + col] = f2bf(acc[mt][nt][r]);
        }
    }
}

// Fragment-layout store: 8 coalesced uint4 per thread.
__device__ __forceinline__ void store_frag(
    f32x4 (&acc)[4][4], short* __restrict__ planeTile)
{
    uint4* p = (uint4*)planeTile;
    const int tid = threadIdx.x;
    #pragma unroll
    for (int c = 0; c < 8; ++c) {
        int nt = c >> 1, mt0 = (c & 1) * 2;
        uint4 o = {pack2bf(acc[mt0][nt][0],     acc[mt0][nt][1]),
                   pack2bf(acc[mt0][nt][2],     acc[mt0][nt][3]),
                   pack2bf(acc[mt0 + 1][nt][0], acc[mt0 + 1][nt][1]),
                   pack2bf(acc[mt0 + 1][nt][2], acc[mt0 + 1][nt][3])};
        p[c * 256 + tid] = o;
    }
}

// Reduce one fragment chunk (tile, c) across SK planes -> row-major output.
template <bool OUT_F32>
__device__ __forceinline__ void reduce_unit(
    const short* __restrict__ P, size_t planeU4, int SK,
    int tile, int c, int tilesX, void* __restrict__ Out, int ldc,
    const float* __restrict__ bias)
{
    const int bm = (tile / tilesX) << 7;
    const int bn = (tile % tilesX) << 7;
    const int tid  = threadIdx.x;
    const int wave = tid >> 6;
    const int lane = tid & 63;
    const int wm   = (wave >> 1) << 6;
    const int wn   = (wave & 1) << 6;
    const int l16  = lane & 15;
    const int quad = lane >> 4;
    const int nt   = c >> 1, mt0 = (c & 1) * 2;

    const uint4* P4 = (const uint4*)P;
    const size_t base = (size_t)tile * 2048 + (size_t)c * 256 + tid;
    float f[8] = {0, 0, 0, 0, 0, 0, 0, 0};
    for (int z = 0; z < SK; ++z) {
        uint4 v = P4[(size_t)z * planeU4 + base];
        f[0] += bflo(v.x); f[1] += bfhi(v.x);
        f[2] += bflo(v.y); f[3] += bfhi(v.y);
        f[4] += bflo(v.z); f[5] += bfhi(v.z);
        f[6] += bflo(v.w); f[7] += bfhi(v.w);
    }
    const int col = bn + wn + nt * 16 + l16;
    float bv = 0.f;
    if (OUT_F32) bv = bias[col];
    #pragma unroll
    for (int j = 0; j < 8; ++j) {
        int mt  = mt0 + (j >> 2);
        int row = bm + wm + mt * 16 + quad * 4 + (j & 3);
        if (OUT_F32)
            ((float*)Out)[(size_t)row * ldc + col] = f[j] + bv;
        else
            ((short*)Out)[(size_t)row * ldc + col] = f2bf(f[j]);
    }
}

// ---------------------------------------------------------------------------
// Merged dispatch, 1024 blocks:
//   [0,512):   folded stage-1 split-K GEMM (SK=4) -> s1 partial planes.
//     tile tx<4:  Xp cols [0,512)    = xee @ B1e[0:512]^T    (Kpart=256)
//     tile tx<8:  Xp cols [512,1024) = xeo @ B1e[512:1024]^T (Kpart=256)
//     tile tx>=8: Xp cols [1024,2048)= xo  @ B1o^T           (Kpart=512)
//   [512,1024): W2 = B2' @ VS?^T (K=1024 after k-fold; SK=4, Kpart=256).
// ---------------------------------------------------------------------------
__global__ __launch_bounds__(256, 2) void gemm_s1w2(
    const short* __restrict__ xee, const short* __restrict__ xeo,
    const short* __restrict__ xo,
    const short* __restrict__ B1e, const short* __restrict__ B1o,
    const short* __restrict__ B2,
    const short* __restrict__ VSe, const short* __restrict__ VSo,
    short* __restrict__ P, short* __restrict__ PW)
{
    __shared__ __align__(16) short As[2 * 128 * 64];
    __shared__ __align__(16) short Bs[2 * 128 * 64];

    f32x4 acc[4][4];
    #pragma unroll
    for (int i = 0; i < 4; ++i)
        #pragma unroll
        for (int j = 0; j < 4; ++j)
            acc[i][j] = (f32x4){0.f, 0.f, 0.f, 0.f};

    const int raw = (int)blockIdx.x;
    if (raw < 512) {
        const int u    = xcd_swizzle(raw, 512);
        const int z    = u >> 7;          // SK = 4
        const int tile = u & 127;         // 8 x 16 tiles
        const int tx   = tile & 15, ty = tile >> 4;
        const int bm   = ty << 7;
        if (tx < 8) {
            // even-freq half: K=1024, Kpart=256
            const short* A = ((tx & 4) ? xeo : xee) + (size_t)z * 256;
            const short* B = B1e + (size_t)z * 256;
            tile_core(A, 1024, B, 1024, 256, As, Bs, bm, tx << 7, acc);
        } else {
            // odd-freq half: K=2048, Kpart=512
            const short* A = xo + (size_t)z * 512;
            const short* B = B1o + (size_t)z * 512;
            tile_core(A, 2048, B, 2048, 512, As, Bs, bm, (tx & 7) << 7, acc);
        }
        store_frag(acc, P + (size_t)z * 2097152 + (size_t)tile * 16384);
    } else {
        const int u    = xcd_swizzle(raw - 512, 512);
        const int z    = u >> 7;          // SK = 4, Kpart = 256
        const int tile = u & 127;         // 8(p) x 16(f) tiles
        const int bm   = (tile >> 4) << 7;
        const int bn   = (tile & 15) << 7;
        const short* Bv = (bm < 512) ? VSe : VSo;   // freq-parity group

        tile_core(B2 + (size_t)z * 256, 1024, Bv + (size_t)z * 256, 1024,
                  256, As, Bs, bm, bn, acc);
        store_frag(acc, PW + (size_t)z * 2097152 + (size_t)tile * 16384);
    }
}

// Merged reduce: blocks [0,1024) -> Xp from P; [1024,2048) -> W2 from PW.
__global__ __launch_bounds__(256) void reduce_s1w2(
    const short* __restrict__ P, const short* __restrict__ PW,
    short* __restrict__ Xp, short* __restrict__ W2)
{
    const int b   = (int)blockIdx.x;
    const int sub = b & 1023;
    if (b < 1024)
        reduce_unit<false>(P,  (size_t)2097152 >> 3, 4, sub >> 3, sub & 7,
                           16, Xp, 2048, nullptr);
    else
        reduce_unit<false>(PW, (size_t)2097152 >> 3, 4, sub >> 3, sub & 7,
                           16, W2, 2048, nullptr);
}

// ---------------------------------------------------------------------------
// Generic split-K GEMM into fragment-layout bf16 partial planes.
// ---------------------------------------------------------------------------
__global__ __launch_bounds__(256, 2) void gemm_sk_frag(
    const short* __restrict__ A, int lda,
    const short* __restrict__ B, int ldb,
    short* __restrict__ P, size_t planeShorts, int Kpart,
    int tileShift, int tilesXShift)
{
    __shared__ __align__(16) short As[2 * 128 * 64];
    __shared__ __align__(16) short Bs[2 * 128 * 64];

    f32x4 acc[4][4];
    #pragma unroll
    for (int i = 0; i < 4; ++i)
        #pragma unroll
        for (int j = 0; j < 4; ++j)
            acc[i][j] = (f32x4){0.f, 0.f, 0.f, 0.f};

    const int u    = xcd_swizzle((int)blockIdx.x, (int)gridDim.x);
    const int z    = u >> tileShift;
    const int tile = u & ((1 << tileShift) - 1);
    const int bm   = (tile >> tilesXShift) << 7;
    const int bn   = (tile & ((1 << tilesXShift) - 1)) << 7;

    tile_core(A + (size_t)z * Kpart, lda, B + (size_t)z * Kpart, ldb, Kpart,
              As, Bs, bm, bn, acc);
    store_frag(acc, P + (size_t)z * planeShorts + (size_t)tile * 16384);
}

template <bool OUT_F32>
__global__ __launch_bounds__(256) void reduce_frag(
    const short* __restrict__ P, size_t planeShorts, int SK,
    int tilesX, void* __restrict__ Out, int ldc,
    const float* __restrict__ bias)
{
    reduce_unit<OUT_F32>(P, planeShorts >> 3, SK,
                         (int)(blockIdx.x >> 3), (int)(blockIdx.x & 7),
                         tilesX, Out, ldc, bias);
}

// ---------------------------------------------------------------------------
// Direct GEMM (full K): final out stage (f32 + bias) and fallback path.
// ---------------------------------------------------------------------------
template <bool OUT_F32>
__global__ __launch_bounds__(256, 2) void gemm_direct(
    const short* __restrict__ A, int lda,
    const short* __restrict__ B, int ldb,
    void* __restrict__ Cv, int ldc,
    const float* __restrict__ bias, int K)
{
    __shared__ __align__(16) short As[2 * 128 * 64];
    __shared__ __align__(16) short Bs[2 * 128 * 64];

    f32x4 acc[4][4];
    #pragma unroll
    for (int i = 0; i < 4; ++i)
        #pragma unroll
        for (int j = 0; j < 4; ++j)
            acc[i][j] = (f32x4){0.f, 0.f, 0.f, 0.f};

    const int bm = blockIdx.y << 7;
    const int bn = blockIdx.x << 7;
    tile_core(A, lda, B, ldb, K, As, Bs, bm, bn, acc);

    const int tid  = threadIdx.x;
    const int wave = tid >> 6;
    const int lane = tid & 63;
    const int wm   = (wave >> 1) << 6;
    const int wn   = (wave & 1) << 6;
    const int l16  = lane & 15;
    const int quad = lane >> 4;

    if (OUT_F32) {
        float* C = (float*)Cv;
        #pragma unroll
        for (int nt = 0; nt < 4; ++nt) {
            int col = bn + wn + nt * 16 + l16;
            float bv = bias ? bias[col] : 0.f;
            #pragma unroll
            for (int mt = 0; mt < 4; ++mt) {
                int rowb = bm + wm + mt * 16 + quad * 4;
                #pragma unroll
                for (int r = 0; r < 4; ++r)
                    C[(size_t)(rowb + r) * ldc + col] = acc[mt][nt][r] + bv;
            }
        }
    } else {
        store_tile_bf16(acc, (short*)Cv, ldc, bm, bn);
    }
}

extern "C" void kernel_launch(void* const* d_in, const int* in_sizes, int n_in,
                              void* d_out, int out_size, void* d_ws, size_t ws_size,
                              hipStream_t stream) {
    const float* x    = (const float*)d_in[0];
    const float* Ur   = (const float*)d_in[1];
    const float* Ui   = (const float*)d_in[2];
    const float* S    = (const float*)d_in[3];
    const float* Vr   = (const float*)d_in[4];
    const float* Vi   = (const float*)d_in[5];
    const float* bias = (const float*)d_in[6];
    float* out = (float*)d_out;

    short* ws    = (short*)d_ws;
    short* xee   = ws;                                  // 1024*1024
    short* xeo   = xee   + (size_t)1024 * 1024;         // 1024*1024
    short* xo    = xeo   + (size_t)1024 * 1024;         // 1024*2048
    short* B1e   = xo    + (size_t)1024 * 2048;         // 1024*1024
    short* B1o   = B1e   + (size_t)1024 * 1024;         // 1024*2048
    short* VSe   = B1o   + (size_t)1024 * 2048;         // 2048*1024
    short* VSo   = VSe   + (size_t)2048 * 1024;         // 2048*1024
    short* B2    = VSo   + (size_t)2048 * 1024;         // 1024*1024
    short* Ucat  = B2    + (size_t)1024 * 1024;         // 4096*1024
    short* Xp    = Ucat  + (size_t)4096 * 1024;         // 1024*2048
    short* W2    = Xp    + (size_t)1024 * 2048;         // 1024*2048
    short* Gm    = W2    + (size_t)1024 * 2048;         // 1024*1024
    short* Pp    = Gm    + (size_t)1024 * 1024;         // partials 8.39M shorts
    short* PW    = Pp    + (size_t)8388608;             // W2 partials 8.39M

    const size_t need = (size_t)((char*)(PW + (size_t)8388608) - (char*)d_ws);

    aux_all8<<<dim3(5120), 256, 0, stream>>>(
        x, Ur, Ui, S, Vr, Vi, xee, xeo, xo, B1e, B1o, VSe, VSo, B2, Ucat);

    if (ws_size >= need) {
        // [s1 || W2] merged (1024 blocks, both SK=4)
        gemm_s1w2<<<dim3(1024), 256, 0, stream>>>(
            xee, xeo, xo, B1e, B1o, B2, VSe, VSo, Pp, PW);
        reduce_s1w2<<<dim3(2048), 256, 0, stream>>>(Pp, PW, Xp, W2);

        // G = Xp @ W2^T (1024x1024, K=2048; SK=8, Kpart=256, 512 blocks)
        gemm_sk_frag<<<dim3(512), 256, 0, stream>>>(
            Xp, 2048, W2, 2048, Pp, (size_t)1048576, 256, 6, 3);
        reduce_frag<false><<<dim3(512), 256, 0, stream>>>(
            Pp, (size_t)1048576, 8, 8, Gm, 1024, nullptr);

        // out = G @ Ucat^T + bias (1024x4096, K=1024) -- direct (R11-proven)
        gemm_direct<true><<<dim3(32, 8), 256, 0, stream>>>(
            Gm, 1024, Ucat, 1024, out, 4096, bias, 1024);
    } else {
        // Fallback: direct GEMMs, pointer-offset outputs for s1 thirds.
        gemm_direct<false><<<dim3(4, 8), 256, 0, stream>>>(
            xee, 1024, B1e, 1024, Xp, 2048, nullptr, 1024);
        gemm_direct<false><<<dim3(4, 8), 256, 0, stream>>>(
            xeo, 1024, B1e + (size_t)512 * 1024, 1024, Xp + 512, 2048,
            nullptr, 1024);
        gemm_direct<false><<<dim3(8, 8), 256, 0, stream>>>(
            xo, 2048, B1o, 2048, Xp + 1024, 2048, nullptr, 2048);
        gemm_direct<false><<<dim3(16, 4), 256, 0, stream>>>(
            B2, 1024, VSe, 1024, W2, 2048, nullptr, 1024);
        gemm_direct<false><<<dim3(16, 4), 256, 0, stream>>>(
            B2 + (size_t)512 * 1024, 1024, VSo, 1024,
            W2 + (size_t)512 * 2048, 2048, nullptr, 1024);
        gemm_direct<false><<<dim3(8, 8), 256, 0, stream>>>(
            Xp, 2048, W2, 2048, Gm, 1024, nullptr, 2048);
        gemm_direct<true><<<dim3(32, 8), 256, 0, stream>>>(
            Gm, 1024, Ucat, 1024, out, 4096, bias, 1024);
    }
}